// Round 14
// baseline (208.077 us; speedup 1.0000x reference)
//
#include <hip/hip_runtime.h>
#include <hip/hip_bf16.h>
#include <stdint.h>

#define T_TOK 2048
#define HID   1024
#define FFN_  2048
#define NEXP  8
#define NPAIR 4096   // T_TOK * top_k(2)
#define MAXTILE 40   // sum over experts of ceil(cnt/128) <= 32+8
#define EXPELEM ((size_t)HID * FFN_)

typedef __bf16 bf16;
typedef __bf16 bf16x8 __attribute__((ext_vector_type(8)));
typedef __bf16 bf16x4 __attribute__((ext_vector_type(4)));
typedef float  f32x4  __attribute__((ext_vector_type(4)));
typedef unsigned int u32;

// ---- workspace layout (bytes) ----
#define OFF_EXP   0
#define OFF_NT    64
#define OFF_TTE   128
#define OFF_TTM   512
#define OFF_TOK   1024
#define OFF_WGT   (OFF_TOK + 16384)
#define OFF_XG    65536
#define OFF_H1    (OFF_XG + (size_t)NPAIR*HID*2)
#define OFF_PB    (OFF_H1 + (size_t)NPAIR*FFN_*2)     // f32 [2][T_TOK][HID] = 16 MB
#define OFF_WT    (OFF_PB + (size_t)2*T_TOK*HID*4)

__device__ __forceinline__ void gld16(const void* g, void* l) {
    __builtin_amdgcn_global_load_lds(
        (const __attribute__((address_space(1))) u32*)g,
        (__attribute__((address_space(3))) u32*)l, 16, 0, 0);
}

// ---------------- routing: stable counting sort of pairs by expert ----------
__global__ void route_kernel(const uint32_t* __restrict__ te_raw,
                             const float* __restrict__ top_w,
                             int* __restrict__ expert_off,
                             int* __restrict__ ntile_g,
                             int* __restrict__ tte, int* __restrict__ ttm,
                             int* __restrict__ tok, float* __restrict__ wgt)
{
    __shared__ int counts[NEXP];
    __shared__ int offs[NEXP + 1];
    __shared__ int is64_s;
    int tid = threadIdx.x;
    int wv = tid >> 6, lane = tid & 63;
    if (wv == 0) {                       // lane-parallel int64 detection
        int bad = (te_raw[2 * lane + 1] != 0u);
        unsigned long long m = __ballot(bad);
        if (lane == 0) is64_s = (m == 0ull);
    }
    __syncthreads();
    int is64 = is64_s;
    int cnt = 0;
    for (int base = 0; base < NPAIR; base += 64) {
        int p = base + lane;
        int eid = is64 ? (int)te_raw[2*p] : (int)te_raw[p];
        unsigned long long m = __ballot(eid == wv);
        cnt += __popcll(m);
    }
    if (lane == 0) counts[wv] = cnt;
    __syncthreads();
    if (tid == 0) {
        int s = 0;
        for (int e2 = 0; e2 < NEXP; ++e2) { offs[e2] = s; expert_off[e2] = s; s += counts[e2]; }
        offs[NEXP] = s; expert_off[NEXP] = s;
        int nt = 0;
        for (int e2 = 0; e2 < NEXP; ++e2)
            for (int m = offs[e2]; m < offs[e2 + 1]; m += 128) { tte[nt] = e2; ttm[nt] = m; ++nt; }
        *ntile_g = nt;
    }
    __syncthreads();
    int off = offs[wv];
    for (int base = 0; base < NPAIR; base += 64) {
        int p = base + lane;
        int eid = is64 ? (int)te_raw[2*p] : (int)te_raw[p];
        unsigned long long m = __ballot(eid == wv);
        if (eid == wv) {
            int pre = __popcll(m & ((1ull << lane) - 1ull));
            int s = off + pre;
            tok[s] = p >> 1;
            wgt[s] = top_w[p];
        }
        off += __popcll(m);
    }
}

// ---------------- gather x rows -> bf16 -------------------------------------
__global__ void gather_kernel(const float* __restrict__ x,
                              const int* __restrict__ tok,
                              bf16* __restrict__ Xg)
{
    int p = blockIdx.x;
    int t = tok[p];
    const float4* src = (const float4*)(x + (size_t)t * HID);
    float4 v = src[threadIdx.x];
    bf16x4 o;
    o[0] = (bf16)v.x; o[1] = (bf16)v.y; o[2] = (bf16)v.z; o[3] = (bf16)v.w;
    *(bf16x4*)(Xg + (size_t)p * HID + threadIdx.x * 4) = o;
}

// --------- transpose v4 (up/gate only): f32 [R][C] -> tile-image bf16 -------
__global__ void __launch_bounds__(256)
transpose_v4(const float* __restrict__ in1, bf16* __restrict__ out1,
             const float* __restrict__ in2, bf16* __restrict__ out2,
             int nz1, int R, int C)
{
    __shared__ u32 tile32[4][64 * 32];   // 32 KB
    int z = blockIdx.z;
    const float* in = (z < nz1) ? in1 : in2;
    bf16* o         = (z < nz1) ? out1 : out2;
    int e = (z < nz1) ? z : z - nz1;
    in += (size_t)e * R * C;
    o  += (size_t)e * R * C;
    int kt = blockIdx.x, nq = blockIdx.y;
    int k0 = kt * 64, c0 = nq * 256;
    int tid = threadIdx.x;
    int rbase = tid >> 6;
    int c4 = tid & 63;
    int grp = c4 >> 4, cq = c4 & 15;
    int fp0 = cq * 2;
    #pragma unroll
    for (int it = 0; it < 16; ++it) {
        int r = rbase + it * 4;
        float4 v = *(const float4*)(in + (size_t)(k0 + r) * C + c0 + c4 * 4);
        union { bf16 h[2]; u32 w; } a, b;
        a.h[0] = (bf16)v.x; a.h[1] = (bf16)v.y;
        b.h[0] = (bf16)v.z; b.h[1] = (bf16)v.w;
        tile32[grp][r * 32 + (fp0       ^ (r & 31))] = a.w;
        tile32[grp][r * 32 + ((fp0 + 1) ^ (r & 31))] = b.w;
    }
    __syncthreads();
    int RT = R >> 6;
    #pragma unroll
    for (int it2 = 0; it2 < 8; ++it2) {
        int gg = it2 * 256 + tid;
        int group = gg >> 9, g = gg & 511;
        int f = g >> 3;
        int k8 = ((g & 7) ^ (f & 7)) * 8;
        union { bf16 h[8]; } pk;
        #pragma unroll
        for (int j = 0; j < 8; ++j) {
            u32 u = tile32[group][(k8 + j) * 32 + ((f >> 1) ^ ((k8 + j) & 31))];
            pk.h[j] = (f & 1) ? ((bf16*)&u)[1] : ((bf16*)&u)[0];
        }
        bf16* tbase = o + ((size_t)(nq * 4 + group) * RT + kt) * 4096;
        *(bf16x8*)(tbase + (size_t)g * 8) = *(bf16x8*)&pk;
    }
}

// ---------------- GEMM1: H1 = silu(Xg@Wu) * (Xg@Wg) per expert ---------------
__global__ void __launch_bounds__(256)
moe_upgate(const bf16* __restrict__ Xg,
           const bf16* __restrict__ wuT, const bf16* __restrict__ wgT,
           const int* __restrict__ expert_off, const int* __restrict__ ntile_g,
           const int* __restrict__ tte, const int* __restrict__ ttm,
           int eb, int gcnt, bf16* __restrict__ H1)
{
    int ty = blockIdx.y;
    if (ty >= *ntile_g) return;
    int e = tte[ty];
    if (e < eb || e >= eb + gcnt) return;
    int m0 = ttm[ty];
    int p1 = expert_off[e + 1];
    int n0 = blockIdx.x * 64;
    __shared__ bf16 As [128 * 64];
    __shared__ bf16 Bus[64 * 64];
    __shared__ bf16 Bgs[64 * 64];
    int tid = threadIdx.x, lane = tid & 63, wv = tid >> 6;
    int wm = wv >> 1, wn = wv & 1;
    int l16 = lane & 15, lhi = lane >> 4;
    f32x4 accU[4][2] = {};
    f32x4 accG[4][2] = {};

    const bf16* aptr[4]; u32 alds[4];
    #pragma unroll
    for (int c = 0; c < 4; ++c) {
        int g = c * 256 + tid;
        int r = g >> 3, pos = g & 7;
        int gr = m0 + r; if (gr >= p1) gr = p1 - 1;
        int gsrc = pos ^ (r & 7);
        aptr[c] = Xg + (size_t)gr * HID + gsrc * 8;
        alds[c] = g * 16;
    }
    size_t tb0 = (size_t)(e - eb) * EXPELEM + (size_t)(n0 >> 6) * (HID >> 6) * 4096;
    const bf16* buptr[2]; const bf16* bgptr[2]; u32 blds[2];
    #pragma unroll
    for (int c = 0; c < 2; ++c) {
        int g = c * 256 + tid;
        buptr[c] = wuT + tb0 + (size_t)g * 8;
        bgptr[c] = wgT + tb0 + (size_t)g * 8;
        blds[c] = g * 16;
    }
    u32 aro[2][4], bro[2][2];
    #pragma unroll
    for (int ks = 0; ks < 2; ++ks) {
        #pragma unroll
        for (int fm = 0; fm < 4; ++fm) {
            int r = wm * 64 + fm * 16 + l16;
            aro[ks][fm] = r * 128 + ((u32)((ks * 4 + lhi) ^ (r & 7))) * 16;
        }
        #pragma unroll
        for (int fn = 0; fn < 2; ++fn) {
            int fr = wn * 32 + fn * 16 + l16;
            bro[ks][fn] = fr * 128 + ((u32)((ks * 4 + lhi) ^ (fr & 7))) * 16;
        }
    }

    for (int t = 0; t < HID / 64; ++t) {
        #pragma unroll
        for (int c = 0; c < 4; ++c) { gld16(aptr[c], (char*)As + alds[c]); aptr[c] += 64; }
        #pragma unroll
        for (int c = 0; c < 2; ++c) {
            gld16(buptr[c], (char*)Bus + blds[c]); buptr[c] += 4096;
            gld16(bgptr[c], (char*)Bgs + blds[c]); bgptr[c] += 4096;
        }
        __syncthreads();
        #pragma unroll
        for (int ks = 0; ks < 2; ++ks) {
            bf16x8 af[4];
            #pragma unroll
            for (int fm = 0; fm < 4; ++fm)
                af[fm] = *(const bf16x8*)((char*)As + aro[ks][fm]);
            #pragma unroll
            for (int fn = 0; fn < 2; ++fn) {
                bf16x8 bu = *(const bf16x8*)((char*)Bus + bro[ks][fn]);
                bf16x8 bg = *(const bf16x8*)((char*)Bgs + bro[ks][fn]);
                #pragma unroll
                for (int fm = 0; fm < 4; ++fm) {
                    accU[fm][fn] = __builtin_amdgcn_mfma_f32_16x16x32_bf16(af[fm], bu, accU[fm][fn], 0, 0, 0);
                    accG[fm][fn] = __builtin_amdgcn_mfma_f32_16x16x32_bf16(af[fm], bg, accG[fm][fn], 0, 0, 0);
                }
            }
        }
        __syncthreads();
    }
    #pragma unroll
    for (int fm = 0; fm < 4; ++fm)
    #pragma unroll
    for (int fn = 0; fn < 2; ++fn)
    #pragma unroll
    for (int rg = 0; rg < 4; ++rg) {
        int r = m0 + wm * 64 + fm * 16 + lhi * 4 + rg;
        if (r < p1) {
            float u = accU[fm][fn][rg], g = accG[fm][fn][rg];
            float h = (u / (1.f + __expf(-u))) * g;
            int fc = n0 + wn * 32 + fn * 16 + l16;
            H1[(size_t)r * FFN_ + fc] = (bf16)h;
        }
    }
}

// ---------------- GEMM2 (direct fp32 weights, K-split x2): ------------------
// pb[kh] += (H1[:, kh*1024:+1024] @ Wd[kh half]) * wgt  (2 atomic adds/slot
// elem — commutative -> deterministic). Combine sums the two slots.
__global__ void __launch_bounds__(256)
moe_down(const bf16* __restrict__ H1, const float* __restrict__ Wd,
         const int* __restrict__ expert_off, const int* __restrict__ ntile_g,
         const int* __restrict__ tte, const int* __restrict__ ttm,
         const int* __restrict__ tok, const float* __restrict__ wgt,
         float* __restrict__ pb)
{
    int ty = blockIdx.y;
    if (ty >= *ntile_g) return;
    int kh = blockIdx.z;                 // K half: rows [kh*1024, +1024)
    int e = tte[ty];
    int m0 = ttm[ty];
    int p1 = expert_off[e + 1];
    int n0 = blockIdx.x * 64;
    __shared__ bf16 As[128 * 64];
    __shared__ bf16 Bs [64 * 64];
    __shared__ float wgt_s[128];
    __shared__ int   tok_s[128];
    const float* wd = Wd + (size_t)e * FFN_ * HID + (size_t)kh * (FFN_ / 2) * HID;
    int tid = threadIdx.x, lane = tid & 63, wv = tid >> 6;
    int wm = wv >> 1, wn = wv & 1;
    int l16 = lane & 15, lhi = lane >> 4;
    if (tid < 128) {
        int r = m0 + tid;
        if (r < p1) { wgt_s[tid] = wgt[r]; tok_s[tid] = tok[r]; }
        else        { wgt_s[tid] = 0.f;    tok_s[tid] = 0; }
    }
    f32x4 acc[4][2] = {};

    const bf16* aptr[4]; u32 alds[4];
    #pragma unroll
    for (int c = 0; c < 4; ++c) {
        int g = c * 256 + tid;
        int r = g >> 3, pos = g & 7;
        int gr = m0 + r; if (gr >= p1) gr = p1 - 1;
        int gsrc = pos ^ (r & 7);
        aptr[c] = H1 + (size_t)gr * FFN_ + kh * (FFN_ / 2) + gsrc * 8;
        alds[c] = g * 16;
    }
    int f = lane;
    int c0 = wv, c1 = wv + 4;
    const float* bsrc0 = wd + (size_t)(c0 * 8) * HID + n0 + f;
    const float* bsrc1 = wd + (size_t)(c1 * 8) * HID + n0 + f;
    u32 bw0 = f * 128 + ((u32)(c0 ^ (f & 7))) * 16;
    u32 bw1 = f * 128 + ((u32)(c1 ^ (f & 7))) * 16;
    u32 aro[2][4], bro[2][2];
    #pragma unroll
    for (int ks = 0; ks < 2; ++ks) {
        #pragma unroll
        for (int fm = 0; fm < 4; ++fm) {
            int r = wm * 64 + fm * 16 + l16;
            aro[ks][fm] = r * 128 + ((u32)((ks * 4 + lhi) ^ (r & 7))) * 16;
        }
        #pragma unroll
        for (int fn = 0; fn < 2; ++fn) {
            int fr = wn * 32 + fn * 16 + l16;
            bro[ks][fn] = fr * 128 + ((u32)((ks * 4 + lhi) ^ (fr & 7))) * 16;
        }
    }

    for (int t = 0; t < FFN_ / 128; ++t) {   // 16 K-steps of 64 (half of K)
        #pragma unroll
        for (int c = 0; c < 4; ++c) { gld16(aptr[c], (char*)As + alds[c]); aptr[c] += 64; }
        bf16x8 pb0, pb1;
        #pragma unroll
        for (int kk = 0; kk < 8; ++kk) pb0[kk] = (bf16)bsrc0[(size_t)kk * HID];
        #pragma unroll
        for (int kk = 0; kk < 8; ++kk) pb1[kk] = (bf16)bsrc1[(size_t)kk * HID];
        *(bf16x8*)((char*)Bs + bw0) = pb0;
        *(bf16x8*)((char*)Bs + bw1) = pb1;
        bsrc0 += 64 * HID; bsrc1 += 64 * HID;
        __syncthreads();
        #pragma unroll
        for (int ks = 0; ks < 2; ++ks) {
            bf16x8 af[4];
            #pragma unroll
            for (int fm = 0; fm < 4; ++fm)
                af[fm] = *(const bf16x8*)((char*)As + aro[ks][fm]);
            #pragma unroll
            for (int fn = 0; fn < 2; ++fn) {
                bf16x8 bd = *(const bf16x8*)((char*)Bs + bro[ks][fn]);
                #pragma unroll
                for (int fm = 0; fm < 4; ++fm)
                    acc[fm][fn] = __builtin_amdgcn_mfma_f32_16x16x32_bf16(af[fm], bd, acc[fm][fn], 0, 0, 0);
            }
        }
        __syncthreads();
    }
    #pragma unroll
    for (int fm = 0; fm < 4; ++fm)
    #pragma unroll
    for (int fn = 0; fn < 2; ++fn)
    #pragma unroll
    for (int rg = 0; rg < 4; ++rg) {
        int rl = wm * 64 + fm * 16 + lhi * 4 + rg;
        if (m0 + rl < p1) {
            float v = acc[fm][fn][rg] * wgt_s[rl];
            atomicAdd(pb + ((size_t)kh * T_TOK + tok_s[rl]) * HID
                         + n0 + wn * 32 + fn * 16 + l16, v);
        }
    }
}

// ---------------- combine two K-half slots ----------------------------------
__global__ void combine_kernel(const float* __restrict__ pb, float* __restrict__ out)
{
    size_t i = (size_t)blockIdx.x * blockDim.x + threadIdx.x;
    const float4* a = (const float4*)pb;
    const float4* b = (const float4*)(pb + (size_t)T_TOK * HID);
    float4 va = a[i], vb = b[i];
    float4 r;
    r.x = va.x + vb.x; r.y = va.y + vb.y; r.z = va.z + vb.z; r.w = va.w + vb.w;
    ((float4*)out)[i] = r;
}

extern "C" void kernel_launch(void* const* d_in, const int* in_sizes, int n_in,
                              void* d_out, int out_size, void* d_ws, size_t ws_size,
                              hipStream_t stream)
{
    const float*    x      = (const float*)d_in[0];
    const float*    top_w  = (const float*)d_in[2];
    const uint32_t* te     = (const uint32_t*)d_in[3];
    const float*    w_up   = (const float*)d_in[4];
    const float*    w_gate = (const float*)d_in[5];
    const float*    w_down = (const float*)d_in[6];
    float* out = (float*)d_out;
    char*  ws  = (char*)d_ws;

    int*   expert_off = (int*)(ws + OFF_EXP);
    int*   ntile_g    = (int*)(ws + OFF_NT);
    int*   tte        = (int*)(ws + OFF_TTE);
    int*   ttm        = (int*)(ws + OFF_TTM);
    int*   tok        = (int*)(ws + OFF_TOK);
    float* wgt        = (float*)(ws + OFF_WGT);
    bf16*  Xg         = (bf16*)(ws + OFF_XG);
    bf16*  H1         = (bf16*)(ws + OFF_H1);
    float* pb         = (float*)(ws + OFF_PB);
    bf16*  WT         = (bf16*)(ws + OFF_WT);

    size_t wtcap = ws_size > (size_t)OFF_WT ? ws_size - (size_t)OFF_WT : 0;
    size_t perexp = EXPELEM * sizeof(bf16);
    int g1 = (int)(wtcap / (2 * perexp));
    g1 = g1 >= 8 ? 8 : g1 >= 4 ? 4 : g1 >= 2 ? 2 : 1;

    hipMemsetAsync(pb, 0, (size_t)2 * T_TOK * HID * sizeof(float), stream);
    hipLaunchKernelGGL(route_kernel, dim3(1), dim3(512), 0, stream,
                       te, top_w, expert_off, ntile_g, tte, ttm, tok, wgt);
    hipLaunchKernelGGL(gather_kernel, dim3(NPAIR), dim3(256), 0, stream,
                       x, tok, Xg);

    for (int eb = 0; eb < NEXP; eb += g1) {
        bf16* wuT = WT;
        bf16* wgT = WT + (size_t)g1 * EXPELEM;
        hipLaunchKernelGGL(transpose_v4, dim3(HID / 64, FFN_ / 256, 2 * g1), dim3(256), 0, stream,
                           w_up + (size_t)eb * EXPELEM, wuT,
                           w_gate + (size_t)eb * EXPELEM, wgT, g1, HID, FFN_);
        hipLaunchKernelGGL(moe_upgate, dim3(FFN_ / 64, MAXTILE), dim3(256), 0, stream,
                           Xg, wuT, wgT, expert_off, ntile_g, tte, ttm, eb, g1, H1);
    }
    hipLaunchKernelGGL(moe_down, dim3(HID / 64, MAXTILE, 2), dim3(256), 0, stream,
                       H1, w_down, expert_off, ntile_g, tte, ttm, tok, wgt, pb);
    hipLaunchKernelGGL(combine_kernel, dim3((T_TOK * HID / 4) / 256), dim3(256), 0, stream,
                       pb, out);
}

// Round 15
// 198.014 us; speedup vs baseline: 1.0508x; 1.0508x over previous
//
#include <hip/hip_runtime.h>
#include <hip/hip_bf16.h>
#include <stdint.h>

#define T_TOK 2048
#define HID   1024
#define FFN_  2048
#define NEXP  8
#define NPAIR 4096   // T_TOK * top_k(2)
#define MAXTILE 40   // sum over experts of ceil(cnt/128) <= 32+8
#define EXPELEM ((size_t)HID * FFN_)

typedef __bf16 bf16;
typedef __bf16 bf16x8 __attribute__((ext_vector_type(8)));
typedef __bf16 bf16x4 __attribute__((ext_vector_type(4)));
typedef float  f32x4  __attribute__((ext_vector_type(4)));
typedef unsigned int u32;

// ---- workspace layout (bytes) ----
#define OFF_EXP   0
#define OFF_NT    64
#define OFF_TTE   128
#define OFF_TTM   512
#define OFF_TOK   1024
#define OFF_WGT   (OFF_TOK + 16384)
#define OFF_XG    65536
#define OFF_H1    (OFF_XG + (size_t)NPAIR*HID*2)
#define OFF_WT    (OFF_H1 + (size_t)NPAIR*FFN_*2)

__device__ __forceinline__ void gld16(const void* g, void* l) {
    __builtin_amdgcn_global_load_lds(
        (const __attribute__((address_space(1))) u32*)g,
        (__attribute__((address_space(3))) u32*)l, 16, 0, 0);
}

// ---------------- routing: stable counting sort of pairs by expert ----------
__global__ void route_kernel(const uint32_t* __restrict__ te_raw,
                             const float* __restrict__ top_w,
                             int* __restrict__ expert_off,
                             int* __restrict__ ntile_g,
                             int* __restrict__ tte, int* __restrict__ ttm,
                             int* __restrict__ tok, float* __restrict__ wgt)
{
    __shared__ int counts[NEXP];
    __shared__ int offs[NEXP + 1];
    __shared__ int is64_s;
    int tid = threadIdx.x;
    int wv = tid >> 6, lane = tid & 63;
    if (wv == 0) {                       // lane-parallel int64 detection
        int bad = (te_raw[2 * lane + 1] != 0u);
        unsigned long long m = __ballot(bad);
        if (lane == 0) is64_s = (m == 0ull);
    }
    __syncthreads();
    int is64 = is64_s;
    int cnt = 0;
    for (int base = 0; base < NPAIR; base += 64) {
        int p = base + lane;
        int eid = is64 ? (int)te_raw[2*p] : (int)te_raw[p];
        unsigned long long m = __ballot(eid == wv);
        cnt += __popcll(m);
    }
    if (lane == 0) counts[wv] = cnt;
    __syncthreads();
    if (tid == 0) {
        int s = 0;
        for (int e2 = 0; e2 < NEXP; ++e2) { offs[e2] = s; expert_off[e2] = s; s += counts[e2]; }
        offs[NEXP] = s; expert_off[NEXP] = s;
        int nt = 0;
        for (int e2 = 0; e2 < NEXP; ++e2)
            for (int m = offs[e2]; m < offs[e2 + 1]; m += 128) { tte[nt] = e2; ttm[nt] = m; ++nt; }
        *ntile_g = nt;
    }
    __syncthreads();
    int off = offs[wv];
    for (int base = 0; base < NPAIR; base += 64) {
        int p = base + lane;
        int eid = is64 ? (int)te_raw[2*p] : (int)te_raw[p];
        unsigned long long m = __ballot(eid == wv);
        if (eid == wv) {
            int pre = __popcll(m & ((1ull << lane) - 1ull));
            int s = off + pre;
            tok[s] = p >> 1;
            wgt[s] = top_w[p];
        }
        off += __popcll(m);
    }
}

// ---------------- gather x rows -> bf16 -------------------------------------
__global__ void gather_kernel(const float* __restrict__ x,
                              const int* __restrict__ tok,
                              bf16* __restrict__ Xg)
{
    int p = blockIdx.x;
    int t = tok[p];
    const float4* src = (const float4*)(x + (size_t)t * HID);
    float4 v = src[threadIdx.x];
    bf16x4 o;
    o[0] = (bf16)v.x; o[1] = (bf16)v.y; o[2] = (bf16)v.z; o[3] = (bf16)v.w;
    *(bf16x4*)(Xg + (size_t)p * HID + threadIdx.x * 4) = o;
}

// --------- transpose v4 (up/gate): f32 [R][C] -> tile-image bf16 ------------
__global__ void __launch_bounds__(256)
transpose_v4(const float* __restrict__ in1, bf16* __restrict__ out1,
             const float* __restrict__ in2, bf16* __restrict__ out2,
             int nz1, int R, int C)
{
    __shared__ u32 tile32[4][64 * 32];   // 32 KB
    int z = blockIdx.z;
    const float* in = (z < nz1) ? in1 : in2;
    bf16* o         = (z < nz1) ? out1 : out2;
    int e = (z < nz1) ? z : z - nz1;
    in += (size_t)e * R * C;
    o  += (size_t)e * R * C;
    int kt = blockIdx.x, nq = blockIdx.y;
    int k0 = kt * 64, c0 = nq * 256;
    int tid = threadIdx.x;
    int rbase = tid >> 6;
    int c4 = tid & 63;
    int grp = c4 >> 4, cq = c4 & 15;
    int fp0 = cq * 2;
    #pragma unroll
    for (int it = 0; it < 16; ++it) {
        int r = rbase + it * 4;
        float4 v = *(const float4*)(in + (size_t)(k0 + r) * C + c0 + c4 * 4);
        union { bf16 h[2]; u32 w; } a, b;
        a.h[0] = (bf16)v.x; a.h[1] = (bf16)v.y;
        b.h[0] = (bf16)v.z; b.h[1] = (bf16)v.w;
        tile32[grp][r * 32 + (fp0       ^ (r & 31))] = a.w;
        tile32[grp][r * 32 + ((fp0 + 1) ^ (r & 31))] = b.w;
    }
    __syncthreads();
    int RT = R >> 6;
    #pragma unroll
    for (int it2 = 0; it2 < 8; ++it2) {
        int gg = it2 * 256 + tid;
        int group = gg >> 9, g = gg & 511;
        int f = g >> 3;
        int k8 = ((g & 7) ^ (f & 7)) * 8;
        union { bf16 h[8]; } pk;
        #pragma unroll
        for (int j = 0; j < 8; ++j) {
            u32 u = tile32[group][(k8 + j) * 32 + ((f >> 1) ^ ((k8 + j) & 31))];
            pk.h[j] = (f & 1) ? ((bf16*)&u)[1] : ((bf16*)&u)[0];
        }
        bf16* tbase = o + ((size_t)(nq * 4 + group) * RT + kt) * 4096;
        *(bf16x8*)(tbase + (size_t)g * 8) = *(bf16x8*)&pk;
    }
}

// --------- conv_down: W_down f32 [FFN][HID] -> tile-images, read-once -------
// Block (kt, ch, e): rows [kt*64,+64), cols [ch*512,+512): reads 2 KB
// segments @ 4 KB stride (ch=0/1 blocks co-resident = complementary -> full
// row streaming); emits 8 images (v3 format) with fully contiguous writes.
__global__ void __launch_bounds__(512)
conv_down(const float* __restrict__ Wd, bf16* __restrict__ wdT)
{
    __shared__ u32 tile32[8][64 * 32];   // 64 KB
    int kt = blockIdx.x, ch = blockIdx.y, e = blockIdx.z;
    const float* in = Wd + (size_t)e * EXPELEM + (size_t)kt * 64 * HID + ch * 512;
    bf16* o = wdT + (size_t)e * EXPELEM;
    int tid = threadIdx.x;
    int c4 = tid & 127;                  // float4 col within the 512-col panel
    int ntl = c4 >> 4, cq = c4 & 15;
    int fp0 = cq * 2;
    #pragma unroll
    for (int it = 0; it < 16; ++it) {
        int r = (tid >> 7) + it * 4;
        float4 v = *(const float4*)(in + (size_t)r * HID + c4 * 4);
        union { bf16 h[2]; u32 w; } a, b;
        a.h[0] = (bf16)v.x; a.h[1] = (bf16)v.y;
        b.h[0] = (bf16)v.z; b.h[1] = (bf16)v.w;
        tile32[ntl][r * 32 + (fp0       ^ (r & 31))] = a.w;
        tile32[ntl][r * 32 + ((fp0 + 1) ^ (r & 31))] = b.w;
    }
    __syncthreads();
    const int RT = FFN_ >> 6;            // 32 k-tiles
    #pragma unroll
    for (int it2 = 0; it2 < 8; ++it2) {  // 8 images, 512 granules each
        int g = tid & 511;
        int f = g >> 3;
        int k8 = ((g & 7) ^ (f & 7)) * 8;
        union { bf16 h[8]; } pk;
        #pragma unroll
        for (int j = 0; j < 8; ++j) {
            u32 u = tile32[it2][(k8 + j) * 32 + ((f >> 1) ^ ((k8 + j) & 31))];
            pk.h[j] = (f & 1) ? ((bf16*)&u)[1] : ((bf16*)&u)[0];
        }
        bf16* tbase = o + ((size_t)(ch * 8 + it2) * RT + kt) * 4096;
        *(bf16x8*)(tbase + (size_t)g * 8) = *(bf16x8*)&pk;
    }
}

// ---------------- GEMM1: H1 = silu(Xg@Wu) * (Xg@Wg) per expert ---------------
__global__ void __launch_bounds__(256)
moe_upgate(const bf16* __restrict__ Xg,
           const bf16* __restrict__ wuT, const bf16* __restrict__ wgT,
           const int* __restrict__ expert_off, const int* __restrict__ ntile_g,
           const int* __restrict__ tte, const int* __restrict__ ttm,
           int eb, int gcnt, bf16* __restrict__ H1)
{
    int ty = blockIdx.y;
    if (ty >= *ntile_g) return;
    int e = tte[ty];
    if (e < eb || e >= eb + gcnt) return;
    int m0 = ttm[ty];
    int p1 = expert_off[e + 1];
    int n0 = blockIdx.x * 64;
    __shared__ bf16 As [128 * 64];
    __shared__ bf16 Bus[64 * 64];
    __shared__ bf16 Bgs[64 * 64];
    int tid = threadIdx.x, lane = tid & 63, wv = tid >> 6;
    int wm = wv >> 1, wn = wv & 1;
    int l16 = lane & 15, lhi = lane >> 4;
    f32x4 accU[4][2] = {};
    f32x4 accG[4][2] = {};

    const bf16* aptr[4]; u32 alds[4];
    #pragma unroll
    for (int c = 0; c < 4; ++c) {
        int g = c * 256 + tid;
        int r = g >> 3, pos = g & 7;
        int gr = m0 + r; if (gr >= p1) gr = p1 - 1;
        int gsrc = pos ^ (r & 7);
        aptr[c] = Xg + (size_t)gr * HID + gsrc * 8;
        alds[c] = g * 16;
    }
    size_t tb0 = (size_t)(e - eb) * EXPELEM + (size_t)(n0 >> 6) * (HID >> 6) * 4096;
    const bf16* buptr[2]; const bf16* bgptr[2]; u32 blds[2];
    #pragma unroll
    for (int c = 0; c < 2; ++c) {
        int g = c * 256 + tid;
        buptr[c] = wuT + tb0 + (size_t)g * 8;
        bgptr[c] = wgT + tb0 + (size_t)g * 8;
        blds[c] = g * 16;
    }
    u32 aro[2][4], bro[2][2];
    #pragma unroll
    for (int ks = 0; ks < 2; ++ks) {
        #pragma unroll
        for (int fm = 0; fm < 4; ++fm) {
            int r = wm * 64 + fm * 16 + l16;
            aro[ks][fm] = r * 128 + ((u32)((ks * 4 + lhi) ^ (r & 7))) * 16;
        }
        #pragma unroll
        for (int fn = 0; fn < 2; ++fn) {
            int fr = wn * 32 + fn * 16 + l16;
            bro[ks][fn] = fr * 128 + ((u32)((ks * 4 + lhi) ^ (fr & 7))) * 16;
        }
    }

    for (int t = 0; t < HID / 64; ++t) {
        #pragma unroll
        for (int c = 0; c < 4; ++c) { gld16(aptr[c], (char*)As + alds[c]); aptr[c] += 64; }
        #pragma unroll
        for (int c = 0; c < 2; ++c) {
            gld16(buptr[c], (char*)Bus + blds[c]); buptr[c] += 4096;
            gld16(bgptr[c], (char*)Bgs + blds[c]); bgptr[c] += 4096;
        }
        __syncthreads();
        #pragma unroll
        for (int ks = 0; ks < 2; ++ks) {
            bf16x8 af[4];
            #pragma unroll
            for (int fm = 0; fm < 4; ++fm)
                af[fm] = *(const bf16x8*)((char*)As + aro[ks][fm]);
            #pragma unroll
            for (int fn = 0; fn < 2; ++fn) {
                bf16x8 bu = *(const bf16x8*)((char*)Bus + bro[ks][fn]);
                bf16x8 bg = *(const bf16x8*)((char*)Bgs + bro[ks][fn]);
                #pragma unroll
                for (int fm = 0; fm < 4; ++fm) {
                    accU[fm][fn] = __builtin_amdgcn_mfma_f32_16x16x32_bf16(af[fm], bu, accU[fm][fn], 0, 0, 0);
                    accG[fm][fn] = __builtin_amdgcn_mfma_f32_16x16x32_bf16(af[fm], bg, accG[fm][fn], 0, 0, 0);
                }
            }
        }
        __syncthreads();
    }
    #pragma unroll
    for (int fm = 0; fm < 4; ++fm)
    #pragma unroll
    for (int fn = 0; fn < 2; ++fn)
    #pragma unroll
    for (int rg = 0; rg < 4; ++rg) {
        int r = m0 + wm * 64 + fm * 16 + lhi * 4 + rg;
        if (r < p1) {
            float u = accU[fm][fn][rg], g = accG[fm][fn][rg];
            float h = (u / (1.f + __expf(-u))) * g;
            int fc = n0 + wn * 32 + fn * 16 + l16;
            H1[(size_t)r * FFN_ + fc] = (bf16)h;
        }
    }
}

// ---------------- GEMM2 (image weights, R11-verified): ----------------------
// out += (H1 @ Wdown) * wgt (atomic, 2 adds/elem)
__global__ void __launch_bounds__(256)
moe_down(const bf16* __restrict__ H1, const bf16* __restrict__ wdT,
         const int* __restrict__ expert_off, const int* __restrict__ ntile_g,
         const int* __restrict__ tte, const int* __restrict__ ttm,
         const int* __restrict__ tok, const float* __restrict__ wgt,
         float* __restrict__ out)
{
    int ty = blockIdx.y;
    if (ty >= *ntile_g) return;
    int e = tte[ty];
    int m0 = ttm[ty];
    int p1 = expert_off[e + 1];
    int n0 = blockIdx.x * 64;
    __shared__ bf16 As[128 * 64];
    __shared__ bf16 Bs [64 * 64];
    __shared__ float wgt_s[128];
    __shared__ int   tok_s[128];
    int tid = threadIdx.x, lane = tid & 63, wv = tid >> 6;
    int wm = wv >> 1, wn = wv & 1;
    int l16 = lane & 15, lhi = lane >> 4;
    if (tid < 128) {
        int r = m0 + tid;
        if (r < p1) { wgt_s[tid] = wgt[r]; tok_s[tid] = tok[r]; }
        else        { wgt_s[tid] = 0.f;    tok_s[tid] = 0; }
    }
    f32x4 acc[4][2] = {};

    const bf16* aptr[4]; u32 alds[4];
    #pragma unroll
    for (int c = 0; c < 4; ++c) {
        int g = c * 256 + tid;
        int r = g >> 3, pos = g & 7;
        int gr = m0 + r; if (gr >= p1) gr = p1 - 1;
        int gsrc = pos ^ (r & 7);
        aptr[c] = H1 + (size_t)gr * FFN_ + gsrc * 8;
        alds[c] = g * 16;
    }
    size_t tb0 = (size_t)e * EXPELEM + (size_t)(n0 >> 6) * (FFN_ >> 6) * 4096;
    const bf16* bptr[2]; u32 blds[2];
    #pragma unroll
    for (int c = 0; c < 2; ++c) {
        int g = c * 256 + tid;
        bptr[c] = wdT + tb0 + (size_t)g * 8;
        blds[c] = g * 16;
    }
    u32 aro[2][4], bro[2][2];
    #pragma unroll
    for (int ks = 0; ks < 2; ++ks) {
        #pragma unroll
        for (int fm = 0; fm < 4; ++fm) {
            int r = wm * 64 + fm * 16 + l16;
            aro[ks][fm] = r * 128 + ((u32)((ks * 4 + lhi) ^ (r & 7))) * 16;
        }
        #pragma unroll
        for (int fn = 0; fn < 2; ++fn) {
            int fr = wn * 32 + fn * 16 + l16;
            bro[ks][fn] = fr * 128 + ((u32)((ks * 4 + lhi) ^ (fr & 7))) * 16;
        }
    }

    for (int t = 0; t < FFN_ / 64; ++t) {
        #pragma unroll
        for (int c = 0; c < 4; ++c) { gld16(aptr[c], (char*)As + alds[c]); aptr[c] += 64; }
        #pragma unroll
        for (int c = 0; c < 2; ++c) { gld16(bptr[c], (char*)Bs + blds[c]); bptr[c] += 4096; }
        __syncthreads();
        #pragma unroll
        for (int ks = 0; ks < 2; ++ks) {
            bf16x8 af[4];
            #pragma unroll
            for (int fm = 0; fm < 4; ++fm)
                af[fm] = *(const bf16x8*)((char*)As + aro[ks][fm]);
            #pragma unroll
            for (int fn = 0; fn < 2; ++fn) {
                bf16x8 bd = *(const bf16x8*)((char*)Bs + bro[ks][fn]);
                #pragma unroll
                for (int fm = 0; fm < 4; ++fm)
                    acc[fm][fn] = __builtin_amdgcn_mfma_f32_16x16x32_bf16(af[fm], bd, acc[fm][fn], 0, 0, 0);
            }
        }
        __syncthreads();
    }
    #pragma unroll
    for (int fm = 0; fm < 4; ++fm)
    #pragma unroll
    for (int fn = 0; fn < 2; ++fn)
    #pragma unroll
    for (int rg = 0; rg < 4; ++rg) {
        int rl = wm * 64 + fm * 16 + lhi * 4 + rg;
        if (m0 + rl < p1) {
            float v = acc[fm][fn][rg] * wgt_s[rl];
            atomicAdd(out + (size_t)tok_s[rl] * HID + n0 + wn * 32 + fn * 16 + l16, v);
        }
    }
}

extern "C" void kernel_launch(void* const* d_in, const int* in_sizes, int n_in,
                              void* d_out, int out_size, void* d_ws, size_t ws_size,
                              hipStream_t stream)
{
    const float*    x      = (const float*)d_in[0];
    const float*    top_w  = (const float*)d_in[2];
    const uint32_t* te     = (const uint32_t*)d_in[3];
    const float*    w_up   = (const float*)d_in[4];
    const float*    w_gate = (const float*)d_in[5];
    const float*    w_down = (const float*)d_in[6];
    float* out = (float*)d_out;
    char*  ws  = (char*)d_ws;

    int*   expert_off = (int*)(ws + OFF_EXP);
    int*   ntile_g    = (int*)(ws + OFF_NT);
    int*   tte        = (int*)(ws + OFF_TTE);
    int*   ttm        = (int*)(ws + OFF_TTM);
    int*   tok        = (int*)(ws + OFF_TOK);
    float* wgt        = (float*)(ws + OFF_WGT);
    bf16*  Xg         = (bf16*)(ws + OFF_XG);
    bf16*  H1         = (bf16*)(ws + OFF_H1);
    bf16*  WT         = (bf16*)(ws + OFF_WT);

    size_t wtcap = ws_size > (size_t)OFF_WT ? ws_size - (size_t)OFF_WT : 0;
    size_t perexp = EXPELEM * sizeof(bf16);
    int g1 = (int)(wtcap / (2 * perexp));
    g1 = g1 >= 8 ? 8 : g1 >= 4 ? 4 : g1 >= 2 ? 2 : 1;

    hipMemsetAsync(out, 0, (size_t)out_size * sizeof(float), stream);
    hipLaunchKernelGGL(route_kernel, dim3(1), dim3(512), 0, stream,
                       te, top_w, expert_off, ntile_g, tte, ttm, tok, wgt);
    hipLaunchKernelGGL(gather_kernel, dim3(NPAIR), dim3(256), 0, stream,
                       x, tok, Xg);

    // up/gate: v4 transpose to images, then image-based GEMM
    for (int eb = 0; eb < NEXP; eb += g1) {
        bf16* wuT = WT;
        bf16* wgT = WT + (size_t)g1 * EXPELEM;
        hipLaunchKernelGGL(transpose_v4, dim3(HID / 64, FFN_ / 256, 2 * g1), dim3(256), 0, stream,
                           w_up + (size_t)eb * EXPELEM, wuT,
                           w_gate + (size_t)eb * EXPELEM, wgT, g1, HID, FFN_);
        hipLaunchKernelGGL(moe_upgate, dim3(FFN_ / 64, MAXTILE), dim3(256), 0, stream,
                           Xg, wuT, wgT, expert_off, ntile_g, tte, ttm, eb, g1, H1);
    }
    // down: read-once streaming conversion to images (reuses WT), then GEMM
    hipLaunchKernelGGL(conv_down, dim3(FFN_ / 64, 2, NEXP), dim3(512), 0, stream,
                       w_down, WT);
    hipLaunchKernelGGL(moe_down, dim3(HID / 64, MAXTILE), dim3(256), 0, stream,
                       H1, WT, expert_off, ntile_g, tte, ttm, tok, wgt, out);
}

// Round 16
// 184.656 us; speedup vs baseline: 1.1268x; 1.0723x over previous
//
#include <hip/hip_runtime.h>
#include <hip/hip_bf16.h>
#include <stdint.h>

#define T_TOK 2048
#define HID   1024
#define FFN_  2048
#define NEXP  8
#define NPAIR 4096   // T_TOK * top_k(2)
#define MAXTILE 40   // sum over experts of ceil(cnt/128) <= 32+8
#define EXPELEM ((size_t)HID * FFN_)

typedef __bf16 bf16;
typedef __bf16 bf16x8 __attribute__((ext_vector_type(8)));
typedef __bf16 bf16x4 __attribute__((ext_vector_type(4)));
typedef float  f32x4  __attribute__((ext_vector_type(4)));
typedef float  f32x4v __attribute__((ext_vector_type(4)));
typedef unsigned int u32;

// ---- workspace layout (bytes) ----
#define OFF_EXP   0
#define OFF_NT    64
#define OFF_TTE   128
#define OFF_TTM   512
#define OFF_TOK   1024
#define OFF_WGT   (OFF_TOK + 16384)
#define OFF_XG    65536
#define OFF_H1    (OFF_XG + (size_t)NPAIR*HID*2)
#define OFF_WT    (OFF_H1 + (size_t)NPAIR*FFN_*2)   // [wuT 32M][wgT 32M][wdT 32M]

__device__ __forceinline__ void gld16(const void* g, void* l) {
    __builtin_amdgcn_global_load_lds(
        (const __attribute__((address_space(1))) u32*)g,
        (__attribute__((address_space(3))) u32*)l, 16, 0, 0);
}

// ---------------- routing: stable counting sort of pairs by expert ----------
__global__ void route_kernel(const uint32_t* __restrict__ te_raw,
                             const float* __restrict__ top_w,
                             int* __restrict__ expert_off,
                             int* __restrict__ ntile_g,
                             int* __restrict__ tte, int* __restrict__ ttm,
                             int* __restrict__ tok, float* __restrict__ wgt)
{
    __shared__ int counts[NEXP];
    __shared__ int offs[NEXP + 1];
    __shared__ int is64_s;
    int tid = threadIdx.x;
    int wv = tid >> 6, lane = tid & 63;
    if (wv == 0) {                       // lane-parallel int64 detection
        int bad = (te_raw[2 * lane + 1] != 0u);
        unsigned long long m = __ballot(bad);
        if (lane == 0) is64_s = (m == 0ull);
    }
    __syncthreads();
    int is64 = is64_s;
    int cnt = 0;
    for (int base = 0; base < NPAIR; base += 64) {
        int p = base + lane;
        int eid = is64 ? (int)te_raw[2*p] : (int)te_raw[p];
        unsigned long long m = __ballot(eid == wv);
        cnt += __popcll(m);
    }
    if (lane == 0) counts[wv] = cnt;
    __syncthreads();
    if (tid == 0) {
        int s = 0;
        for (int e2 = 0; e2 < NEXP; ++e2) { offs[e2] = s; expert_off[e2] = s; s += counts[e2]; }
        offs[NEXP] = s; expert_off[NEXP] = s;
        int nt = 0;
        for (int e2 = 0; e2 < NEXP; ++e2)
            for (int m = offs[e2]; m < offs[e2 + 1]; m += 128) { tte[nt] = e2; ttm[nt] = m; ++nt; }
        *ntile_g = nt;
    }
    __syncthreads();
    int off = offs[wv];
    for (int base = 0; base < NPAIR; base += 64) {
        int p = base + lane;
        int eid = is64 ? (int)te_raw[2*p] : (int)te_raw[p];
        unsigned long long m = __ballot(eid == wv);
        if (eid == wv) {
            int pre = __popcll(m & ((1ull << lane) - 1ull));
            int s = off + pre;
            tok[s] = p >> 1;
            wgt[s] = top_w[p];
        }
        off += __popcll(m);
    }
}

// ---------------- gather x rows -> bf16 -------------------------------------
__global__ void gather_kernel(const float* __restrict__ x,
                              const int* __restrict__ tok,
                              bf16* __restrict__ Xg)
{
    int p = blockIdx.x;
    int t = tok[p];
    const float4* src = (const float4*)(x + (size_t)t * HID);
    float4 v = src[threadIdx.x];
    bf16x4 o;
    o[0] = (bf16)v.x; o[1] = (bf16)v.y; o[2] = (bf16)v.z; o[3] = (bf16)v.w;
    *(bf16x4*)(Xg + (size_t)p * HID + threadIdx.x * 4) = o;
}

// --------- transpose v5: f32 [R][C] -> tile-image bf16, MLP+NT reads --------
// All 16 reads issued back-to-back (16 outstanding/wave) as non-temporal,
// THEN convert+LDS-write. Image format identical to v3/v4 (R11-verified).
__global__ void __launch_bounds__(256)
transpose_v5(const float* __restrict__ in1, bf16* __restrict__ out1,
             const float* __restrict__ in2, bf16* __restrict__ out2,
             int nz1, int R, int C)
{
    __shared__ u32 tile32[4][64 * 32];   // 32 KB
    int z = blockIdx.z;
    const float* in = (z < nz1) ? in1 : in2;
    bf16* o         = (z < nz1) ? out1 : out2;
    int e = (z < nz1) ? z : z - nz1;
    in += (size_t)e * R * C;
    o  += (size_t)e * R * C;
    int kt = blockIdx.x, nq = blockIdx.y;
    int k0 = kt * 64, c0 = nq * 256;
    int tid = threadIdx.x;
    int rbase = tid >> 6;
    int c4 = tid & 63;
    int grp = c4 >> 4, cq = c4 & 15;
    int fp0 = cq * 2;
    const float* base = in + (size_t)(k0 + rbase) * C + c0 + c4 * 4;
    // phase 1: 16 outstanding non-temporal reads
    f32x4v rb[16];
    #pragma unroll
    for (int it = 0; it < 16; ++it)
        rb[it] = __builtin_nontemporal_load((const f32x4v*)(base + (size_t)it * 4 * C));
    // phase 2: convert + LDS write
    #pragma unroll
    for (int it = 0; it < 16; ++it) {
        int r = rbase + it * 4;
        union { bf16 h[2]; u32 w; } a, b;
        a.h[0] = (bf16)rb[it][0]; a.h[1] = (bf16)rb[it][1];
        b.h[0] = (bf16)rb[it][2]; b.h[1] = (bf16)rb[it][3];
        tile32[grp][r * 32 + (fp0       ^ (r & 31))] = a.w;
        tile32[grp][r * 32 + ((fp0 + 1) ^ (r & 31))] = b.w;
    }
    __syncthreads();
    int RT = R >> 6;
    #pragma unroll
    for (int it2 = 0; it2 < 8; ++it2) {
        int gg = it2 * 256 + tid;
        int group = gg >> 9, g = gg & 511;
        int f = g >> 3;
        int k8 = ((g & 7) ^ (f & 7)) * 8;
        union { bf16 h[8]; } pk;
        #pragma unroll
        for (int j = 0; j < 8; ++j) {
            u32 u = tile32[group][(k8 + j) * 32 + ((f >> 1) ^ ((k8 + j) & 31))];
            pk.h[j] = (f & 1) ? ((bf16*)&u)[1] : ((bf16*)&u)[0];
        }
        bf16* tbase = o + ((size_t)(nq * 4 + group) * RT + kt) * 4096;
        *(bf16x8*)(tbase + (size_t)g * 8) = *(bf16x8*)&pk;
    }
}

// ---------------- GEMM1: H1 = silu(Xg@Wu) * (Xg@Wg) per expert ---------------
// (R11-verified: single-buffer, hoisted invariants, tile-image B staging)
__global__ void __launch_bounds__(256)
moe_upgate(const bf16* __restrict__ Xg,
           const bf16* __restrict__ wuT, const bf16* __restrict__ wgT,
           const int* __restrict__ expert_off, const int* __restrict__ ntile_g,
           const int* __restrict__ tte, const int* __restrict__ ttm,
           bf16* __restrict__ H1)
{
    int ty = blockIdx.y;
    if (ty >= *ntile_g) return;
    int e = tte[ty];
    int m0 = ttm[ty];
    int p1 = expert_off[e + 1];
    int n0 = blockIdx.x * 64;
    __shared__ bf16 As [128 * 64];
    __shared__ bf16 Bus[64 * 64];
    __shared__ bf16 Bgs[64 * 64];
    int tid = threadIdx.x, lane = tid & 63, wv = tid >> 6;
    int wm = wv >> 1, wn = wv & 1;
    int l16 = lane & 15, lhi = lane >> 4;
    f32x4 accU[4][2] = {};
    f32x4 accG[4][2] = {};

    const bf16* aptr[4]; u32 alds[4];
    #pragma unroll
    for (int c = 0; c < 4; ++c) {
        int g = c * 256 + tid;
        int r = g >> 3, pos = g & 7;
        int gr = m0 + r; if (gr >= p1) gr = p1 - 1;
        int gsrc = pos ^ (r & 7);
        aptr[c] = Xg + (size_t)gr * HID + gsrc * 8;
        alds[c] = g * 16;
    }
    size_t tb0 = (size_t)e * EXPELEM + (size_t)(n0 >> 6) * (HID >> 6) * 4096;
    const bf16* buptr[2]; const bf16* bgptr[2]; u32 blds[2];
    #pragma unroll
    for (int c = 0; c < 2; ++c) {
        int g = c * 256 + tid;
        buptr[c] = wuT + tb0 + (size_t)g * 8;
        bgptr[c] = wgT + tb0 + (size_t)g * 8;
        blds[c] = g * 16;
    }
    u32 aro[2][4], bro[2][2];
    #pragma unroll
    for (int ks = 0; ks < 2; ++ks) {
        #pragma unroll
        for (int fm = 0; fm < 4; ++fm) {
            int r = wm * 64 + fm * 16 + l16;
            aro[ks][fm] = r * 128 + ((u32)((ks * 4 + lhi) ^ (r & 7))) * 16;
        }
        #pragma unroll
        for (int fn = 0; fn < 2; ++fn) {
            int fr = wn * 32 + fn * 16 + l16;
            bro[ks][fn] = fr * 128 + ((u32)((ks * 4 + lhi) ^ (fr & 7))) * 16;
        }
    }

    for (int t = 0; t < HID / 64; ++t) {
        #pragma unroll
        for (int c = 0; c < 4; ++c) { gld16(aptr[c], (char*)As + alds[c]); aptr[c] += 64; }
        #pragma unroll
        for (int c = 0; c < 2; ++c) {
            gld16(buptr[c], (char*)Bus + blds[c]); buptr[c] += 4096;
            gld16(bgptr[c], (char*)Bgs + blds[c]); bgptr[c] += 4096;
        }
        __syncthreads();
        #pragma unroll
        for (int ks = 0; ks < 2; ++ks) {
            bf16x8 af[4];
            #pragma unroll
            for (int fm = 0; fm < 4; ++fm)
                af[fm] = *(const bf16x8*)((char*)As + aro[ks][fm]);
            #pragma unroll
            for (int fn = 0; fn < 2; ++fn) {
                bf16x8 bu = *(const bf16x8*)((char*)Bus + bro[ks][fn]);
                bf16x8 bg = *(const bf16x8*)((char*)Bgs + bro[ks][fn]);
                #pragma unroll
                for (int fm = 0; fm < 4; ++fm) {
                    accU[fm][fn] = __builtin_amdgcn_mfma_f32_16x16x32_bf16(af[fm], bu, accU[fm][fn], 0, 0, 0);
                    accG[fm][fn] = __builtin_amdgcn_mfma_f32_16x16x32_bf16(af[fm], bg, accG[fm][fn], 0, 0, 0);
                }
            }
        }
        __syncthreads();
    }
    #pragma unroll
    for (int fm = 0; fm < 4; ++fm)
    #pragma unroll
    for (int fn = 0; fn < 2; ++fn)
    #pragma unroll
    for (int rg = 0; rg < 4; ++rg) {
        int r = m0 + wm * 64 + fm * 16 + lhi * 4 + rg;
        if (r < p1) {
            float u = accU[fm][fn][rg], g = accG[fm][fn][rg];
            float h = (u / (1.f + __expf(-u))) * g;
            int fc = n0 + wn * 32 + fn * 16 + l16;
            H1[(size_t)r * FFN_ + fc] = (bf16)h;
        }
    }
}

// ---------------- GEMM2 (image weights, R11-verified): ----------------------
__global__ void __launch_bounds__(256)
moe_down(const bf16* __restrict__ H1, const bf16* __restrict__ wdT,
         const int* __restrict__ expert_off, const int* __restrict__ ntile_g,
         const int* __restrict__ tte, const int* __restrict__ ttm,
         const int* __restrict__ tok, const float* __restrict__ wgt,
         float* __restrict__ out)
{
    int ty = blockIdx.y;
    if (ty >= *ntile_g) return;
    int e = tte[ty];
    int m0 = ttm[ty];
    int p1 = expert_off[e + 1];
    int n0 = blockIdx.x * 64;
    __shared__ bf16 As[128 * 64];
    __shared__ bf16 Bs [64 * 64];
    __shared__ float wgt_s[128];
    __shared__ int   tok_s[128];
    int tid = threadIdx.x, lane = tid & 63, wv = tid >> 6;
    int wm = wv >> 1, wn = wv & 1;
    int l16 = lane & 15, lhi = lane >> 4;
    if (tid < 128) {
        int r = m0 + tid;
        if (r < p1) { wgt_s[tid] = wgt[r]; tok_s[tid] = tok[r]; }
        else        { wgt_s[tid] = 0.f;    tok_s[tid] = 0; }
    }
    f32x4 acc[4][2] = {};

    const bf16* aptr[4]; u32 alds[4];
    #pragma unroll
    for (int c = 0; c < 4; ++c) {
        int g = c * 256 + tid;
        int r = g >> 3, pos = g & 7;
        int gr = m0 + r; if (gr >= p1) gr = p1 - 1;
        int gsrc = pos ^ (r & 7);
        aptr[c] = H1 + (size_t)gr * FFN_ + gsrc * 8;
        alds[c] = g * 16;
    }
    size_t tb0 = (size_t)e * EXPELEM + (size_t)(n0 >> 6) * (FFN_ >> 6) * 4096;
    const bf16* bptr[2]; u32 blds[2];
    #pragma unroll
    for (int c = 0; c < 2; ++c) {
        int g = c * 256 + tid;
        bptr[c] = wdT + tb0 + (size_t)g * 8;
        blds[c] = g * 16;
    }
    u32 aro[2][4], bro[2][2];
    #pragma unroll
    for (int ks = 0; ks < 2; ++ks) {
        #pragma unroll
        for (int fm = 0; fm < 4; ++fm) {
            int r = wm * 64 + fm * 16 + l16;
            aro[ks][fm] = r * 128 + ((u32)((ks * 4 + lhi) ^ (r & 7))) * 16;
        }
        #pragma unroll
        for (int fn = 0; fn < 2; ++fn) {
            int fr = wn * 32 + fn * 16 + l16;
            bro[ks][fn] = fr * 128 + ((u32)((ks * 4 + lhi) ^ (fr & 7))) * 16;
        }
    }

    for (int t = 0; t < FFN_ / 64; ++t) {
        #pragma unroll
        for (int c = 0; c < 4; ++c) { gld16(aptr[c], (char*)As + alds[c]); aptr[c] += 64; }
        #pragma unroll
        for (int c = 0; c < 2; ++c) { gld16(bptr[c], (char*)Bs + blds[c]); bptr[c] += 4096; }
        __syncthreads();
        #pragma unroll
        for (int ks = 0; ks < 2; ++ks) {
            bf16x8 af[4];
            #pragma unroll
            for (int fm = 0; fm < 4; ++fm)
                af[fm] = *(const bf16x8*)((char*)As + aro[ks][fm]);
            #pragma unroll
            for (int fn = 0; fn < 2; ++fn) {
                bf16x8 bd = *(const bf16x8*)((char*)Bs + bro[ks][fn]);
                #pragma unroll
                for (int fm = 0; fm < 4; ++fm)
                    acc[fm][fn] = __builtin_amdgcn_mfma_f32_16x16x32_bf16(af[fm], bd, acc[fm][fn], 0, 0, 0);
            }
        }
        __syncthreads();
    }
    #pragma unroll
    for (int fm = 0; fm < 4; ++fm)
    #pragma unroll
    for (int fn = 0; fn < 2; ++fn)
    #pragma unroll
    for (int rg = 0; rg < 4; ++rg) {
        int rl = wm * 64 + fm * 16 + lhi * 4 + rg;
        if (m0 + rl < p1) {
            float v = acc[fm][fn][rg] * wgt_s[rl];
            atomicAdd(out + (size_t)tok_s[rl] * HID + n0 + wn * 32 + fn * 16 + l16, v);
        }
    }
}

extern "C" void kernel_launch(void* const* d_in, const int* in_sizes, int n_in,
                              void* d_out, int out_size, void* d_ws, size_t ws_size,
                              hipStream_t stream)
{
    const float*    x      = (const float*)d_in[0];
    const float*    top_w  = (const float*)d_in[2];
    const uint32_t* te     = (const uint32_t*)d_in[3];
    const float*    w_up   = (const float*)d_in[4];
    const float*    w_gate = (const float*)d_in[5];
    const float*    w_down = (const float*)d_in[6];
    float* out = (float*)d_out;
    char*  ws  = (char*)d_ws;

    int*   expert_off = (int*)(ws + OFF_EXP);
    int*   ntile_g    = (int*)(ws + OFF_NT);
    int*   tte        = (int*)(ws + OFF_TTE);
    int*   ttm        = (int*)(ws + OFF_TTM);
    int*   tok        = (int*)(ws + OFF_TOK);
    float* wgt        = (float*)(ws + OFF_WGT);
    bf16*  Xg         = (bf16*)(ws + OFF_XG);
    bf16*  H1         = (bf16*)(ws + OFF_H1);
    bf16*  WT         = (bf16*)(ws + OFF_WT);
    bf16*  wuT = WT;
    bf16*  wgT = WT + 8 * EXPELEM;     // +32 MB
    bf16*  wdT = WT + 16 * EXPELEM;    // +64 MB (ws >= 120 MB proven in R10)

    hipMemsetAsync(out, 0, (size_t)out_size * sizeof(float), stream);
    hipLaunchKernelGGL(route_kernel, dim3(1), dim3(512), 0, stream,
                       te, top_w, expert_off, ntile_g, tte, ttm, tok, wgt);
    hipLaunchKernelGGL(gather_kernel, dim3(NPAIR), dim3(256), 0, stream,
                       x, tok, Xg);

    // weight conversion, both legs up-front (MLP+NT reads)
    hipLaunchKernelGGL(transpose_v5, dim3(HID / 64, FFN_ / 256, 16), dim3(256), 0, stream,
                       w_up, wuT, w_gate, wgT, 8, HID, FFN_);
    hipLaunchKernelGGL(transpose_v5, dim3(FFN_ / 64, HID / 256, 8), dim3(256), 0, stream,
                       w_down, wdT, w_down, wdT, 8, FFN_, HID);

    hipLaunchKernelGGL(moe_upgate, dim3(FFN_ / 64, MAXTILE), dim3(256), 0, stream,
                       Xg, wuT, wgT, expert_off, ntile_g, tte, ttm, H1);
    hipLaunchKernelGGL(moe_down, dim3(HID / 64, MAXTILE), dim3(256), 0, stream,
                       H1, wdT, expert_off, ntile_g, tte, ttm, tok, wgt, out);
}

// Round 17
// 161.185 us; speedup vs baseline: 1.2909x; 1.1456x over previous
//
#include <hip/hip_runtime.h>
#include <hip/hip_bf16.h>
#include <stdint.h>

#define T_TOK 2048
#define HID   1024
#define FFN_  2048
#define NEXP  8
#define NPAIR 4096   // T_TOK * top_k(2)
#define MAXTILE 40   // sum over experts of ceil(cnt/128) <= 32+8
#define EXPELEM ((size_t)HID * FFN_)
#define NSLICE 16    // route slices (waves)

typedef __bf16 bf16;
typedef __bf16 bf16x8 __attribute__((ext_vector_type(8)));
typedef __bf16 bf16x4 __attribute__((ext_vector_type(4)));
typedef float  f32x4  __attribute__((ext_vector_type(4)));
typedef float  f32x4v __attribute__((ext_vector_type(4)));
typedef unsigned int u32;

// ---- workspace layout (bytes) ----
#define OFF_EXP   0
#define OFF_NT    64
#define OFF_TTE   128
#define OFF_TTM   512
#define OFF_TOK   1024
#define OFF_WGT   (OFF_TOK + 16384)
#define OFF_XG    65536
#define OFF_H1    (OFF_XG + (size_t)NPAIR*HID*2)
#define OFF_WT    (OFF_H1 + (size_t)NPAIR*FFN_*2)   // [wuT 32M][wgT 32M][wdT 32M]

__device__ __forceinline__ void gld16(const void* g, void* l) {
    __builtin_amdgcn_global_load_lds(
        (const __attribute__((address_space(1))) u32*)g,
        (__attribute__((address_space(3))) u32*)l, 16, 0, 0);
}

// ---------------- routing: two-level parallel counting sort -----------------
// 1024 threads = 16 waves; wave w owns slice [w*256, w*256+256) (4 iters).
// Stable: slices processed in order, within-slice ballot order preserved ->
// output identical to the serial version.
__global__ void __launch_bounds__(1024)
route_kernel(const uint32_t* __restrict__ te_raw,
             const float* __restrict__ top_w,
             int* __restrict__ expert_off,
             int* __restrict__ ntile_g,
             int* __restrict__ tte, int* __restrict__ ttm,
             int* __restrict__ tok, float* __restrict__ wgt)
{
    __shared__ int cnt[NSLICE][NEXP];
    __shared__ int off[NSLICE][NEXP];   // global base for slice s, expert e
    __shared__ int ebase[NEXP + 1];
    __shared__ int is64_s;
    int tid = threadIdx.x;
    int wv = tid >> 6, lane = tid & 63;

    if (wv == 0) {                       // lane-parallel int64 detection
        int bad = (te_raw[2 * lane + 1] != 0u);
        unsigned long long m = __ballot(bad);
        if (lane == 0) is64_s = (m == 0ull);
    }
    __syncthreads();
    int is64 = is64_s;

    // Phase A: per-slice per-expert counts (4 iters/wave)
    int c[NEXP] = {0,0,0,0,0,0,0,0};
    int eids[4];
    #pragma unroll
    for (int it = 0; it < 4; ++it) {
        int p = wv * 256 + it * 64 + lane;
        int eid = is64 ? (int)te_raw[2*p] : (int)te_raw[p];
        eids[it] = eid;
        #pragma unroll
        for (int e = 0; e < NEXP; ++e) {
            unsigned long long m = __ballot(eid == e);
            c[e] += __popcll(m);
        }
    }
    if (lane == 0)
        #pragma unroll
        for (int e = 0; e < NEXP; ++e) cnt[wv][e] = c[e];
    __syncthreads();

    // Phase B1: 8 threads do the slice-prefix per expert
    if (tid < NEXP) {
        int run = 0;
        for (int s = 0; s < NSLICE; ++s) { off[s][tid] = run; run += cnt[s][tid]; }
        ebase[tid] = run;                // total per expert (temporarily)
    }
    __syncthreads();
    // Phase B2: thread 0: expert prefix + rebase + tile table
    if (tid == 0) {
        int s = 0;
        for (int e = 0; e < NEXP; ++e) { int t = ebase[e]; ebase[e] = s; expert_off[e] = s; s += t; }
        ebase[NEXP] = s; expert_off[NEXP] = s;
        int nt = 0;
        for (int e = 0; e < NEXP; ++e)
            for (int m = ebase[e]; m < ebase[e + 1]; m += 128) { tte[nt] = e; ttm[nt] = m; ++nt; }
        *ntile_g = nt;
    }
    __syncthreads();

    // Phase C: wave w scatters its slice with running per-expert offsets
    int roff[NEXP];
    #pragma unroll
    for (int e = 0; e < NEXP; ++e) roff[e] = ebase[e] + off[wv][e];
    #pragma unroll
    for (int it = 0; it < 4; ++it) {
        int p = wv * 256 + it * 64 + lane;
        int eid = eids[it];
        int dest = -1;
        #pragma unroll
        for (int e = 0; e < NEXP; ++e) {
            unsigned long long m = __ballot(eid == e);
            if (eid == e) dest = roff[e] + __popcll(m & ((1ull << lane) - 1ull));
            roff[e] += __popcll(m);
        }
        tok[dest] = p >> 1;
        wgt[dest] = top_w[p];
    }
}

// ---------------- gather x rows -> bf16 -------------------------------------
__global__ void gather_kernel(const float* __restrict__ x,
                              const int* __restrict__ tok,
                              bf16* __restrict__ Xg)
{
    int p = blockIdx.x;
    int t = tok[p];
    const float4* src = (const float4*)(x + (size_t)t * HID);
    float4 v = src[threadIdx.x];
    bf16x4 o;
    o[0] = (bf16)v.x; o[1] = (bf16)v.y; o[2] = (bf16)v.z; o[3] = (bf16)v.w;
    *(bf16x4*)(Xg + (size_t)p * HID + threadIdx.x * 4) = o;
}

// --------- transpose v5: f32 [R][C] -> tile-image bf16, MLP+NT reads --------
__global__ void __launch_bounds__(256)
transpose_v5(const float* __restrict__ in1, bf16* __restrict__ out1,
             const float* __restrict__ in2, bf16* __restrict__ out2,
             int nz1, int R, int C)
{
    __shared__ u32 tile32[4][64 * 32];   // 32 KB
    int z = blockIdx.z;
    const float* in = (z < nz1) ? in1 : in2;
    bf16* o         = (z < nz1) ? out1 : out2;
    int e = (z < nz1) ? z : z - nz1;
    in += (size_t)e * R * C;
    o  += (size_t)e * R * C;
    int kt = blockIdx.x, nq = blockIdx.y;
    int k0 = kt * 64, c0 = nq * 256;
    int tid = threadIdx.x;
    int rbase = tid >> 6;
    int c4 = tid & 63;
    int grp = c4 >> 4, cq = c4 & 15;
    int fp0 = cq * 2;
    const float* base = in + (size_t)(k0 + rbase) * C + c0 + c4 * 4;
    f32x4v rb[16];
    #pragma unroll
    for (int it = 0; it < 16; ++it)
        rb[it] = __builtin_nontemporal_load((const f32x4v*)(base + (size_t)it * 4 * C));
    #pragma unroll
    for (int it = 0; it < 16; ++it) {
        int r = rbase + it * 4;
        union { bf16 h[2]; u32 w; } a, b;
        a.h[0] = (bf16)rb[it][0]; a.h[1] = (bf16)rb[it][1];
        b.h[0] = (bf16)rb[it][2]; b.h[1] = (bf16)rb[it][3];
        tile32[grp][r * 32 + (fp0       ^ (r & 31))] = a.w;
        tile32[grp][r * 32 + ((fp0 + 1) ^ (r & 31))] = b.w;
    }
    __syncthreads();
    int RT = R >> 6;
    #pragma unroll
    for (int it2 = 0; it2 < 8; ++it2) {
        int gg = it2 * 256 + tid;
        int group = gg >> 9, g = gg & 511;
        int f = g >> 3;
        int k8 = ((g & 7) ^ (f & 7)) * 8;
        union { bf16 h[8]; } pk;
        #pragma unroll
        for (int j = 0; j < 8; ++j) {
            u32 u = tile32[group][(k8 + j) * 32 + ((f >> 1) ^ ((k8 + j) & 31))];
            pk.h[j] = (f & 1) ? ((bf16*)&u)[1] : ((bf16*)&u)[0];
        }
        bf16* tbase = o + ((size_t)(nq * 4 + group) * RT + kt) * 4096;
        *(bf16x8*)(tbase + (size_t)g * 8) = *(bf16x8*)&pk;
    }
}

// ---------------- GEMM1: H1 = silu(Xg@Wu) * (Xg@Wg) per expert ---------------
__global__ void __launch_bounds__(256)
moe_upgate(const bf16* __restrict__ Xg,
           const bf16* __restrict__ wuT, const bf16* __restrict__ wgT,
           const int* __restrict__ expert_off, const int* __restrict__ ntile_g,
           const int* __restrict__ tte, const int* __restrict__ ttm,
           bf16* __restrict__ H1)
{
    int ty = blockIdx.y;
    if (ty >= *ntile_g) return;
    int e = tte[ty];
    int m0 = ttm[ty];
    int p1 = expert_off[e + 1];
    int n0 = blockIdx.x * 64;
    __shared__ bf16 As [128 * 64];
    __shared__ bf16 Bus[64 * 64];
    __shared__ bf16 Bgs[64 * 64];
    int tid = threadIdx.x, lane = tid & 63, wv = tid >> 6;
    int wm = wv >> 1, wn = wv & 1;
    int l16 = lane & 15, lhi = lane >> 4;
    f32x4 accU[4][2] = {};
    f32x4 accG[4][2] = {};

    const bf16* aptr[4]; u32 alds[4];
    #pragma unroll
    for (int c = 0; c < 4; ++c) {
        int g = c * 256 + tid;
        int r = g >> 3, pos = g & 7;
        int gr = m0 + r; if (gr >= p1) gr = p1 - 1;
        int gsrc = pos ^ (r & 7);
        aptr[c] = Xg + (size_t)gr * HID + gsrc * 8;
        alds[c] = g * 16;
    }
    size_t tb0 = (size_t)e * EXPELEM + (size_t)(n0 >> 6) * (HID >> 6) * 4096;
    const bf16* buptr[2]; const bf16* bgptr[2]; u32 blds[2];
    #pragma unroll
    for (int c = 0; c < 2; ++c) {
        int g = c * 256 + tid;
        buptr[c] = wuT + tb0 + (size_t)g * 8;
        bgptr[c] = wgT + tb0 + (size_t)g * 8;
        blds[c] = g * 16;
    }
    u32 aro[2][4], bro[2][2];
    #pragma unroll
    for (int ks = 0; ks < 2; ++ks) {
        #pragma unroll
        for (int fm = 0; fm < 4; ++fm) {
            int r = wm * 64 + fm * 16 + l16;
            aro[ks][fm] = r * 128 + ((u32)((ks * 4 + lhi) ^ (r & 7))) * 16;
        }
        #pragma unroll
        for (int fn = 0; fn < 2; ++fn) {
            int fr = wn * 32 + fn * 16 + l16;
            bro[ks][fn] = fr * 128 + ((u32)((ks * 4 + lhi) ^ (fr & 7))) * 16;
        }
    }

    for (int t = 0; t < HID / 64; ++t) {
        #pragma unroll
        for (int c = 0; c < 4; ++c) { gld16(aptr[c], (char*)As + alds[c]); aptr[c] += 64; }
        #pragma unroll
        for (int c = 0; c < 2; ++c) {
            gld16(buptr[c], (char*)Bus + blds[c]); buptr[c] += 4096;
            gld16(bgptr[c], (char*)Bgs + blds[c]); bgptr[c] += 4096;
        }
        __syncthreads();
        #pragma unroll
        for (int ks = 0; ks < 2; ++ks) {
            bf16x8 af[4];
            #pragma unroll
            for (int fm = 0; fm < 4; ++fm)
                af[fm] = *(const bf16x8*)((char*)As + aro[ks][fm]);
            #pragma unroll
            for (int fn = 0; fn < 2; ++fn) {
                bf16x8 bu = *(const bf16x8*)((char*)Bus + bro[ks][fn]);
                bf16x8 bg = *(const bf16x8*)((char*)Bgs + bro[ks][fn]);
                #pragma unroll
                for (int fm = 0; fm < 4; ++fm) {
                    accU[fm][fn] = __builtin_amdgcn_mfma_f32_16x16x32_bf16(af[fm], bu, accU[fm][fn], 0, 0, 0);
                    accG[fm][fn] = __builtin_amdgcn_mfma_f32_16x16x32_bf16(af[fm], bg, accG[fm][fn], 0, 0, 0);
                }
            }
        }
        __syncthreads();
    }
    #pragma unroll
    for (int fm = 0; fm < 4; ++fm)
    #pragma unroll
    for (int fn = 0; fn < 2; ++fn)
    #pragma unroll
    for (int rg = 0; rg < 4; ++rg) {
        int r = m0 + wm * 64 + fm * 16 + lhi * 4 + rg;
        if (r < p1) {
            float u = accU[fm][fn][rg], g = accG[fm][fn][rg];
            float h = (u / (1.f + __expf(-u))) * g;
            int fc = n0 + wn * 32 + fn * 16 + l16;
            H1[(size_t)r * FFN_ + fc] = (bf16)h;
        }
    }
}

// ---------------- GEMM2 (image weights): ------------------------------------
__global__ void __launch_bounds__(256)
moe_down(const bf16* __restrict__ H1, const bf16* __restrict__ wdT,
         const int* __restrict__ expert_off, const int* __restrict__ ntile_g,
         const int* __restrict__ tte, const int* __restrict__ ttm,
         const int* __restrict__ tok, const float* __restrict__ wgt,
         float* __restrict__ out)
{
    int ty = blockIdx.y;
    if (ty >= *ntile_g) return;
    int e = tte[ty];
    int m0 = ttm[ty];
    int p1 = expert_off[e + 1];
    int n0 = blockIdx.x * 64;
    __shared__ bf16 As[128 * 64];
    __shared__ bf16 Bs [64 * 64];
    __shared__ float wgt_s[128];
    __shared__ int   tok_s[128];
    int tid = threadIdx.x, lane = tid & 63, wv = tid >> 6;
    int wm = wv >> 1, wn = wv & 1;
    int l16 = lane & 15, lhi = lane >> 4;
    if (tid < 128) {
        int r = m0 + tid;
        if (r < p1) { wgt_s[tid] = wgt[r]; tok_s[tid] = tok[r]; }
        else        { wgt_s[tid] = 0.f;    tok_s[tid] = 0; }
    }
    f32x4 acc[4][2] = {};

    const bf16* aptr[4]; u32 alds[4];
    #pragma unroll
    for (int c = 0; c < 4; ++c) {
        int g = c * 256 + tid;
        int r = g >> 3, pos = g & 7;
        int gr = m0 + r; if (gr >= p1) gr = p1 - 1;
        int gsrc = pos ^ (r & 7);
        aptr[c] = H1 + (size_t)gr * FFN_ + gsrc * 8;
        alds[c] = g * 16;
    }
    size_t tb0 = (size_t)e * EXPELEM + (size_t)(n0 >> 6) * (FFN_ >> 6) * 4096;
    const bf16* bptr[2]; u32 blds[2];
    #pragma unroll
    for (int c = 0; c < 2; ++c) {
        int g = c * 256 + tid;
        bptr[c] = wdT + tb0 + (size_t)g * 8;
        blds[c] = g * 16;
    }
    u32 aro[2][4], bro[2][2];
    #pragma unroll
    for (int ks = 0; ks < 2; ++ks) {
        #pragma unroll
        for (int fm = 0; fm < 4; ++fm) {
            int r = wm * 64 + fm * 16 + l16;
            aro[ks][fm] = r * 128 + ((u32)((ks * 4 + lhi) ^ (r & 7))) * 16;
        }
        #pragma unroll
        for (int fn = 0; fn < 2; ++fn) {
            int fr = wn * 32 + fn * 16 + l16;
            bro[ks][fn] = fr * 128 + ((u32)((ks * 4 + lhi) ^ (fr & 7))) * 16;
        }
    }

    for (int t = 0; t < FFN_ / 64; ++t) {
        #pragma unroll
        for (int c = 0; c < 4; ++c) { gld16(aptr[c], (char*)As + alds[c]); aptr[c] += 64; }
        #pragma unroll
        for (int c = 0; c < 2; ++c) { gld16(bptr[c], (char*)Bs + blds[c]); bptr[c] += 4096; }
        __syncthreads();
        #pragma unroll
        for (int ks = 0; ks < 2; ++ks) {
            bf16x8 af[4];
            #pragma unroll
            for (int fm = 0; fm < 4; ++fm)
                af[fm] = *(const bf16x8*)((char*)As + aro[ks][fm]);
            #pragma unroll
            for (int fn = 0; fn < 2; ++fn) {
                bf16x8 bd = *(const bf16x8*)((char*)Bs + bro[ks][fn]);
                #pragma unroll
                for (int fm = 0; fm < 4; ++fm)
                    acc[fm][fn] = __builtin_amdgcn_mfma_f32_16x16x32_bf16(af[fm], bd, acc[fm][fn], 0, 0, 0);
            }
        }
        __syncthreads();
    }
    #pragma unroll
    for (int fm = 0; fm < 4; ++fm)
    #pragma unroll
    for (int fn = 0; fn < 2; ++fn)
    #pragma unroll
    for (int rg = 0; rg < 4; ++rg) {
        int rl = wm * 64 + fm * 16 + lhi * 4 + rg;
        if (m0 + rl < p1) {
            float v = acc[fm][fn][rg] * wgt_s[rl];
            atomicAdd(out + (size_t)tok_s[rl] * HID + n0 + wn * 32 + fn * 16 + l16, v);
        }
    }
}

extern "C" void kernel_launch(void* const* d_in, const int* in_sizes, int n_in,
                              void* d_out, int out_size, void* d_ws, size_t ws_size,
                              hipStream_t stream)
{
    const float*    x      = (const float*)d_in[0];
    const float*    top_w  = (const float*)d_in[2];
    const uint32_t* te     = (const uint32_t*)d_in[3];
    const float*    w_up   = (const float*)d_in[4];
    const float*    w_gate = (const float*)d_in[5];
    const float*    w_down = (const float*)d_in[6];
    float* out = (float*)d_out;
    char*  ws  = (char*)d_ws;

    int*   expert_off = (int*)(ws + OFF_EXP);
    int*   ntile_g    = (int*)(ws + OFF_NT);
    int*   tte        = (int*)(ws + OFF_TTE);
    int*   ttm        = (int*)(ws + OFF_TTM);
    int*   tok        = (int*)(ws + OFF_TOK);
    float* wgt        = (float*)(ws + OFF_WGT);
    bf16*  Xg         = (bf16*)(ws + OFF_XG);
    bf16*  H1         = (bf16*)(ws + OFF_H1);
    bf16*  WT         = (bf16*)(ws + OFF_WT);
    bf16*  wuT = WT;
    bf16*  wgT = WT + 8 * EXPELEM;     // +32 MB
    bf16*  wdT = WT + 16 * EXPELEM;    // +64 MB (ws >= 120 MB proven in R10)

    hipMemsetAsync(out, 0, (size_t)out_size * sizeof(float), stream);
    hipLaunchKernelGGL(route_kernel, dim3(1), dim3(1024), 0, stream,
                       te, top_w, expert_off, ntile_g, tte, ttm, tok, wgt);
    hipLaunchKernelGGL(gather_kernel, dim3(NPAIR), dim3(256), 0, stream,
                       x, tok, Xg);

    hipLaunchKernelGGL(transpose_v5, dim3(HID / 64, FFN_ / 256, 16), dim3(256), 0, stream,
                       w_up, wuT, w_gate, wgT, 8, HID, FFN_);
    hipLaunchKernelGGL(transpose_v5, dim3(FFN_ / 64, HID / 256, 8), dim3(256), 0, stream,
                       w_down, wdT, w_down, wdT, 8, FFN_, HID);

    hipLaunchKernelGGL(moe_upgate, dim3(FFN_ / 64, MAXTILE), dim3(256), 0, stream,
                       Xg, wuT, wgT, expert_off, ntile_g, tte, ttm, H1);
    hipLaunchKernelGGL(moe_down, dim3(HID / 64, MAXTILE), dim3(256), 0, stream,
                       H1, wdT, expert_off, ntile_g, tte, ttm, tok, wgt, out);
}

// Round 18
// 154.241 us; speedup vs baseline: 1.3490x; 1.0450x over previous
//
#include <hip/hip_runtime.h>
#include <hip/hip_bf16.h>
#include <stdint.h>

#define T_TOK 2048
#define HID   1024
#define FFN_  2048
#define NEXP  8
#define NPAIR 4096   // T_TOK * top_k(2)
#define MAXTILE 40   // sum over experts of ceil(cnt/128) <= 32+8
#define EXPELEM ((size_t)HID * FFN_)
#define NSLICE 16    // route slices (waves)

typedef __bf16 bf16;
typedef __bf16 bf16x8 __attribute__((ext_vector_type(8)));
typedef __bf16 bf16x4 __attribute__((ext_vector_type(4)));
typedef float  f32x4  __attribute__((ext_vector_type(4)));
typedef float  f32x4v __attribute__((ext_vector_type(4)));
typedef unsigned int u32;

// ---- workspace layout (bytes) ----
#define OFF_EXP   0
#define OFF_NT    64
#define OFF_TTE   128
#define OFF_TTM   512
#define OFF_TOK   1024
#define OFF_WGT   (OFF_TOK + 16384)
#define OFF_XG    65536
#define OFF_H1    (OFF_XG + (size_t)NPAIR*HID*2)
#define OFF_WT    (OFF_H1 + (size_t)NPAIR*FFN_*2)   // [wuT 32M][wgT 32M][wdT 32M]

__device__ __forceinline__ void gld16(const void* g, void* l) {
    __builtin_amdgcn_global_load_lds(
        (const __attribute__((address_space(1))) u32*)g,
        (__attribute__((address_space(3))) u32*)l, 16, 0, 0);
}

// ---------------- routing: two-level parallel counting sort -----------------
__global__ void __launch_bounds__(1024)
route_kernel(const uint32_t* __restrict__ te_raw,
             const float* __restrict__ top_w,
             int* __restrict__ expert_off,
             int* __restrict__ ntile_g,
             int* __restrict__ tte, int* __restrict__ ttm,
             int* __restrict__ tok, float* __restrict__ wgt)
{
    __shared__ int cnt[NSLICE][NEXP];
    __shared__ int off[NSLICE][NEXP];
    __shared__ int ebase[NEXP + 1];
    __shared__ int is64_s;
    int tid = threadIdx.x;
    int wv = tid >> 6, lane = tid & 63;

    if (wv == 0) {
        int bad = (te_raw[2 * lane + 1] != 0u);
        unsigned long long m = __ballot(bad);
        if (lane == 0) is64_s = (m == 0ull);
    }
    __syncthreads();
    int is64 = is64_s;

    int c[NEXP] = {0,0,0,0,0,0,0,0};
    int eids[4];
    #pragma unroll
    for (int it = 0; it < 4; ++it) {
        int p = wv * 256 + it * 64 + lane;
        int eid = is64 ? (int)te_raw[2*p] : (int)te_raw[p];
        eids[it] = eid;
        #pragma unroll
        for (int e = 0; e < NEXP; ++e) {
            unsigned long long m = __ballot(eid == e);
            c[e] += __popcll(m);
        }
    }
    if (lane == 0)
        #pragma unroll
        for (int e = 0; e < NEXP; ++e) cnt[wv][e] = c[e];
    __syncthreads();

    if (tid < NEXP) {
        int run = 0;
        for (int s = 0; s < NSLICE; ++s) { off[s][tid] = run; run += cnt[s][tid]; }
        ebase[tid] = run;
    }
    __syncthreads();
    if (tid == 0) {
        int s = 0;
        for (int e = 0; e < NEXP; ++e) { int t = ebase[e]; ebase[e] = s; expert_off[e] = s; s += t; }
        ebase[NEXP] = s; expert_off[NEXP] = s;
        int nt = 0;
        for (int e = 0; e < NEXP; ++e)
            for (int m = ebase[e]; m < ebase[e + 1]; m += 128) { tte[nt] = e; ttm[nt] = m; ++nt; }
        *ntile_g = nt;
    }
    __syncthreads();

    int roff[NEXP];
    #pragma unroll
    for (int e = 0; e < NEXP; ++e) roff[e] = ebase[e] + off[wv][e];
    #pragma unroll
    for (int it = 0; it < 4; ++it) {
        int p = wv * 256 + it * 64 + lane;
        int eid = eids[it];
        int dest = -1;
        #pragma unroll
        for (int e = 0; e < NEXP; ++e) {
            unsigned long long m = __ballot(eid == e);
            if (eid == e) dest = roff[e] + __popcll(m & ((1ull << lane) - 1ull));
            roff[e] += __popcll(m);
        }
        tok[dest] = p >> 1;
        wgt[dest] = top_w[p];
    }
}

// ---------------- gather x rows -> bf16 -------------------------------------
__global__ void gather_kernel(const float* __restrict__ x,
                              const int* __restrict__ tok,
                              bf16* __restrict__ Xg)
{
    int p = blockIdx.x;
    int t = tok[p];
    const float4* src = (const float4*)(x + (size_t)t * HID);
    float4 v = src[threadIdx.x];
    bf16x4 o;
    o[0] = (bf16)v.x; o[1] = (bf16)v.y; o[2] = (bf16)v.z; o[3] = (bf16)v.w;
    *(bf16x4*)(Xg + (size_t)p * HID + threadIdx.x * 4) = o;
}

// --------- transpose v5: f32 [R][C] -> tile-image bf16, MLP+NT reads --------
__global__ void __launch_bounds__(256)
transpose_v5(const float* __restrict__ in1, bf16* __restrict__ out1,
             const float* __restrict__ in2, bf16* __restrict__ out2,
             int nz1, int R, int C)
{
    __shared__ u32 tile32[4][64 * 32];   // 32 KB
    int z = blockIdx.z;
    const float* in = (z < nz1) ? in1 : in2;
    bf16* o         = (z < nz1) ? out1 : out2;
    int e = (z < nz1) ? z : z - nz1;
    in += (size_t)e * R * C;
    o  += (size_t)e * R * C;
    int kt = blockIdx.x, nq = blockIdx.y;
    int k0 = kt * 64, c0 = nq * 256;
    int tid = threadIdx.x;
    int rbase = tid >> 6;
    int c4 = tid & 63;
    int grp = c4 >> 4, cq = c4 & 15;
    int fp0 = cq * 2;
    const float* base = in + (size_t)(k0 + rbase) * C + c0 + c4 * 4;
    f32x4v rb[16];
    #pragma unroll
    for (int it = 0; it < 16; ++it)
        rb[it] = __builtin_nontemporal_load((const f32x4v*)(base + (size_t)it * 4 * C));
    #pragma unroll
    for (int it = 0; it < 16; ++it) {
        int r = rbase + it * 4;
        union { bf16 h[2]; u32 w; } a, b;
        a.h[0] = (bf16)rb[it][0]; a.h[1] = (bf16)rb[it][1];
        b.h[0] = (bf16)rb[it][2]; b.h[1] = (bf16)rb[it][3];
        tile32[grp][r * 32 + (fp0       ^ (r & 31))] = a.w;
        tile32[grp][r * 32 + ((fp0 + 1) ^ (r & 31))] = b.w;
    }
    __syncthreads();
    int RT = R >> 6;
    #pragma unroll
    for (int it2 = 0; it2 < 8; ++it2) {
        int gg = it2 * 256 + tid;
        int group = gg >> 9, g = gg & 511;
        int f = g >> 3;
        int k8 = ((g & 7) ^ (f & 7)) * 8;
        union { bf16 h[8]; } pk;
        #pragma unroll
        for (int j = 0; j < 8; ++j) {
            u32 u = tile32[group][(k8 + j) * 32 + ((f >> 1) ^ ((k8 + j) & 31))];
            pk.h[j] = (f & 1) ? ((bf16*)&u)[1] : ((bf16*)&u)[0];
        }
        bf16* tbase = o + ((size_t)(nq * 4 + group) * RT + kt) * 4096;
        *(bf16x8*)(tbase + (size_t)g * 8) = *(bf16x8*)&pk;
    }
}

// ---------------- fused: ug-GEMM blocks + w_down transpose blocks -----------
// bid < NGEMM (=1280): GEMM1 H1 = silu(Xg@Wu)*(Xg@Wg) (R17-verified body).
// bid >= NGEMM (1024 blocks): v5-transpose of w_down -> wdT tile images.
// ug is compute-bound (1.85 TB/s of 6.3) -> tr_dn hides in the BW headroom.
#define NGEMM (MAXTILE * (FFN_ / 64))
__global__ void __launch_bounds__(256)
fused_ug(const bf16* __restrict__ Xg,
         const bf16* __restrict__ wuT, const bf16* __restrict__ wgT,
         const int* __restrict__ expert_off, const int* __restrict__ ntile_g,
         const int* __restrict__ tte, const int* __restrict__ ttm,
         bf16* __restrict__ H1,
         const float* __restrict__ Wd, bf16* __restrict__ wdT)
{
    __shared__ char ldsbuf[32768];
    int bid = blockIdx.x;
    int tid = threadIdx.x;

    if (bid >= NGEMM) {
        // ---------- transpose path: w_down f32 [FFN_][HID] -> images ----------
        u32 (*tile32)[64 * 32] = (u32 (*)[64 * 32])ldsbuf;
        int tb = bid - NGEMM;            // 0..1023
        int e = tb >> 7;                 // 128 blocks/expert (32 kt x 4 nq)
        int rem = tb & 127;
        int nq = rem >> 5, kt = rem & 31;
        const float* in = Wd + (size_t)e * EXPELEM;
        bf16* o = wdT + (size_t)e * EXPELEM;
        int k0 = kt * 64, c0 = nq * 256;
        int rbase = tid >> 6;
        int c4 = tid & 63;
        int grp = c4 >> 4, cq = c4 & 15;
        int fp0 = cq * 2;
        const float* base = in + (size_t)(k0 + rbase) * HID + c0 + c4 * 4;
        f32x4v rb[16];
        #pragma unroll
        for (int it = 0; it < 16; ++it)
            rb[it] = __builtin_nontemporal_load((const f32x4v*)(base + (size_t)it * 4 * HID));
        #pragma unroll
        for (int it = 0; it < 16; ++it) {
            int r = rbase + it * 4;
            union { bf16 h[2]; u32 w; } a, b;
            a.h[0] = (bf16)rb[it][0]; a.h[1] = (bf16)rb[it][1];
            b.h[0] = (bf16)rb[it][2]; b.h[1] = (bf16)rb[it][3];
            tile32[grp][r * 32 + (fp0       ^ (r & 31))] = a.w;
            tile32[grp][r * 32 + ((fp0 + 1) ^ (r & 31))] = b.w;
        }
        __syncthreads();
        const int RT = FFN_ >> 6;        // 32
        #pragma unroll
        for (int it2 = 0; it2 < 8; ++it2) {
            int gg = it2 * 256 + tid;
            int group = gg >> 9, g = gg & 511;
            int f = g >> 3;
            int k8 = ((g & 7) ^ (f & 7)) * 8;
            union { bf16 h[8]; } pk;
            #pragma unroll
            for (int j = 0; j < 8; ++j) {
                u32 u = tile32[group][(k8 + j) * 32 + ((f >> 1) ^ ((k8 + j) & 31))];
                pk.h[j] = (f & 1) ? ((bf16*)&u)[1] : ((bf16*)&u)[0];
            }
            bf16* tbase = o + ((size_t)(nq * 4 + group) * RT + kt) * 4096;
            *(bf16x8*)(tbase + (size_t)g * 8) = *(bf16x8*)&pk;
        }
        return;
    }

    // ---------- ug GEMM path (R17-verified body) ----------
    int ty = bid >> 5, bn = bid & 31;    // 32 N-tiles
    if (ty >= *ntile_g) return;
    int e = tte[ty];
    int m0 = ttm[ty];
    int p1 = expert_off[e + 1];
    int n0 = bn * 64;
    bf16* As  = (bf16*)ldsbuf;           // 16 KB
    bf16* Bus = (bf16*)(ldsbuf + 16384); // 8 KB
    bf16* Bgs = (bf16*)(ldsbuf + 24576); // 8 KB
    int lane = tid & 63, wv = tid >> 6;
    int wm = wv >> 1, wn = wv & 1;
    int l16 = lane & 15, lhi = lane >> 4;
    f32x4 accU[4][2] = {};
    f32x4 accG[4][2] = {};

    const bf16* aptr[4]; u32 alds[4];
    #pragma unroll
    for (int c = 0; c < 4; ++c) {
        int g = c * 256 + tid;
        int r = g >> 3, pos = g & 7;
        int gr = m0 + r; if (gr >= p1) gr = p1 - 1;
        int gsrc = pos ^ (r & 7);
        aptr[c] = Xg + (size_t)gr * HID + gsrc * 8;
        alds[c] = g * 16;
    }
    size_t tb0 = (size_t)e * EXPELEM + (size_t)(n0 >> 6) * (HID >> 6) * 4096;
    const bf16* buptr[2]; const bf16* bgptr[2]; u32 blds[2];
    #pragma unroll
    for (int c = 0; c < 2; ++c) {
        int g = c * 256 + tid;
        buptr[c] = wuT + tb0 + (size_t)g * 8;
        bgptr[c] = wgT + tb0 + (size_t)g * 8;
        blds[c] = g * 16;
    }
    u32 aro[2][4], bro[2][2];
    #pragma unroll
    for (int ks = 0; ks < 2; ++ks) {
        #pragma unroll
        for (int fm = 0; fm < 4; ++fm) {
            int r = wm * 64 + fm * 16 + l16;
            aro[ks][fm] = r * 128 + ((u32)((ks * 4 + lhi) ^ (r & 7))) * 16;
        }
        #pragma unroll
        for (int fn = 0; fn < 2; ++fn) {
            int fr = wn * 32 + fn * 16 + l16;
            bro[ks][fn] = fr * 128 + ((u32)((ks * 4 + lhi) ^ (fr & 7))) * 16;
        }
    }

    for (int t = 0; t < HID / 64; ++t) {
        #pragma unroll
        for (int c = 0; c < 4; ++c) { gld16(aptr[c], (char*)As + alds[c]); aptr[c] += 64; }
        #pragma unroll
        for (int c = 0; c < 2; ++c) {
            gld16(buptr[c], (char*)Bus + blds[c]); buptr[c] += 4096;
            gld16(bgptr[c], (char*)Bgs + blds[c]); bgptr[c] += 4096;
        }
        __syncthreads();
        #pragma unroll
        for (int ks = 0; ks < 2; ++ks) {
            bf16x8 af[4];
            #pragma unroll
            for (int fm = 0; fm < 4; ++fm)
                af[fm] = *(const bf16x8*)((char*)As + aro[ks][fm]);
            #pragma unroll
            for (int fn = 0; fn < 2; ++fn) {
                bf16x8 bu = *(const bf16x8*)((char*)Bus + bro[ks][fn]);
                bf16x8 bg = *(const bf16x8*)((char*)Bgs + bro[ks][fn]);
                #pragma unroll
                for (int fm = 0; fm < 4; ++fm) {
                    accU[fm][fn] = __builtin_amdgcn_mfma_f32_16x16x32_bf16(af[fm], bu, accU[fm][fn], 0, 0, 0);
                    accG[fm][fn] = __builtin_amdgcn_mfma_f32_16x16x32_bf16(af[fm], bg, accG[fm][fn], 0, 0, 0);
                }
            }
        }
        __syncthreads();
    }
    #pragma unroll
    for (int fm = 0; fm < 4; ++fm)
    #pragma unroll
    for (int fn = 0; fn < 2; ++fn)
    #pragma unroll
    for (int rg = 0; rg < 4; ++rg) {
        int r = m0 + wm * 64 + fm * 16 + lhi * 4 + rg;
        if (r < p1) {
            float u = accU[fm][fn][rg], g = accG[fm][fn][rg];
            float h = (u / (1.f + __expf(-u))) * g;
            int fc = n0 + wn * 32 + fn * 16 + l16;
            H1[(size_t)r * FFN_ + fc] = (bf16)h;
        }
    }
}

// ---------------- GEMM2 (image weights): ------------------------------------
__global__ void __launch_bounds__(256)
moe_down(const bf16* __restrict__ H1, const bf16* __restrict__ wdT,
         const int* __restrict__ expert_off, const int* __restrict__ ntile_g,
         const int* __restrict__ tte, const int* __restrict__ ttm,
         const int* __restrict__ tok, const float* __restrict__ wgt,
         float* __restrict__ out)
{
    int ty = blockIdx.y;
    if (ty >= *ntile_g) return;
    int e = tte[ty];
    int m0 = ttm[ty];
    int p1 = expert_off[e + 1];
    int n0 = blockIdx.x * 64;
    __shared__ bf16 As[128 * 64];
    __shared__ bf16 Bs [64 * 64];
    __shared__ float wgt_s[128];
    __shared__ int   tok_s[128];
    int tid = threadIdx.x, lane = tid & 63, wv = tid >> 6;
    int wm = wv >> 1, wn = wv & 1;
    int l16 = lane & 15, lhi = lane >> 4;
    if (tid < 128) {
        int r = m0 + tid;
        if (r < p1) { wgt_s[tid] = wgt[r]; tok_s[tid] = tok[r]; }
        else        { wgt_s[tid] = 0.f;    tok_s[tid] = 0; }
    }
    f32x4 acc[4][2] = {};

    const bf16* aptr[4]; u32 alds[4];
    #pragma unroll
    for (int c = 0; c < 4; ++c) {
        int g = c * 256 + tid;
        int r = g >> 3, pos = g & 7;
        int gr = m0 + r; if (gr >= p1) gr = p1 - 1;
        int gsrc = pos ^ (r & 7);
        aptr[c] = H1 + (size_t)gr * FFN_ + gsrc * 8;
        alds[c] = g * 16;
    }
    size_t tb0 = (size_t)e * EXPELEM + (size_t)(n0 >> 6) * (FFN_ >> 6) * 4096;
    const bf16* bptr[2]; u32 blds[2];
    #pragma unroll
    for (int c = 0; c < 2; ++c) {
        int g = c * 256 + tid;
        bptr[c] = wdT + tb0 + (size_t)g * 8;
        blds[c] = g * 16;
    }
    u32 aro[2][4], bro[2][2];
    #pragma unroll
    for (int ks = 0; ks < 2; ++ks) {
        #pragma unroll
        for (int fm = 0; fm < 4; ++fm) {
            int r = wm * 64 + fm * 16 + l16;
            aro[ks][fm] = r * 128 + ((u32)((ks * 4 + lhi) ^ (r & 7))) * 16;
        }
        #pragma unroll
        for (int fn = 0; fn < 2; ++fn) {
            int fr = wn * 32 + fn * 16 + l16;
            bro[ks][fn] = fr * 128 + ((u32)((ks * 4 + lhi) ^ (fr & 7))) * 16;
        }
    }

    for (int t = 0; t < FFN_ / 64; ++t) {
        #pragma unroll
        for (int c = 0; c < 4; ++c) { gld16(aptr[c], (char*)As + alds[c]); aptr[c] += 64; }
        #pragma unroll
        for (int c = 0; c < 2; ++c) { gld16(bptr[c], (char*)Bs + blds[c]); bptr[c] += 4096; }
        __syncthreads();
        #pragma unroll
        for (int ks = 0; ks < 2; ++ks) {
            bf16x8 af[4];
            #pragma unroll
            for (int fm = 0; fm < 4; ++fm)
                af[fm] = *(const bf16x8*)((char*)As + aro[ks][fm]);
            #pragma unroll
            for (int fn = 0; fn < 2; ++fn) {
                bf16x8 bd = *(const bf16x8*)((char*)Bs + bro[ks][fn]);
                #pragma unroll
                for (int fm = 0; fm < 4; ++fm)
                    acc[fm][fn] = __builtin_amdgcn_mfma_f32_16x16x32_bf16(af[fm], bd, acc[fm][fn], 0, 0, 0);
            }
        }
        __syncthreads();
    }
    #pragma unroll
    for (int fm = 0; fm < 4; ++fm)
    #pragma unroll
    for (int fn = 0; fn < 2; ++fn)
    #pragma unroll
    for (int rg = 0; rg < 4; ++rg) {
        int rl = wm * 64 + fm * 16 + lhi * 4 + rg;
        if (m0 + rl < p1) {
            float v = acc[fm][fn][rg] * wgt_s[rl];
            atomicAdd(out + (size_t)tok_s[rl] * HID + n0 + wn * 32 + fn * 16 + l16, v);
        }
    }
}

extern "C" void kernel_launch(void* const* d_in, const int* in_sizes, int n_in,
                              void* d_out, int out_size, void* d_ws, size_t ws_size,
                              hipStream_t stream)
{
    const float*    x      = (const float*)d_in[0];
    const float*    top_w  = (const float*)d_in[2];
    const uint32_t* te     = (const uint32_t*)d_in[3];
    const float*    w_up   = (const float*)d_in[4];
    const float*    w_gate = (const float*)d_in[5];
    const float*    w_down = (const float*)d_in[6];
    float* out = (float*)d_out;
    char*  ws  = (char*)d_ws;

    int*   expert_off = (int*)(ws + OFF_EXP);
    int*   ntile_g    = (int*)(ws + OFF_NT);
    int*   tte        = (int*)(ws + OFF_TTE);
    int*   ttm        = (int*)(ws + OFF_TTM);
    int*   tok        = (int*)(ws + OFF_TOK);
    float* wgt        = (float*)(ws + OFF_WGT);
    bf16*  Xg         = (bf16*)(ws + OFF_XG);
    bf16*  H1         = (bf16*)(ws + OFF_H1);
    bf16*  WT         = (bf16*)(ws + OFF_WT);
    bf16*  wuT = WT;
    bf16*  wgT = WT + 8 * EXPELEM;     // +32 MB
    bf16*  wdT = WT + 16 * EXPELEM;    // +64 MB

    hipMemsetAsync(out, 0, (size_t)out_size * sizeof(float), stream);
    hipLaunchKernelGGL(route_kernel, dim3(1), dim3(1024), 0, stream,
                       te, top_w, expert_off, ntile_g, tte, ttm, tok, wgt);
    hipLaunchKernelGGL(gather_kernel, dim3(NPAIR), dim3(256), 0, stream,
                       x, tok, Xg);

    // up/gate weight conversion (v5)
    hipLaunchKernelGGL(transpose_v5, dim3(HID / 64, FFN_ / 256, 16), dim3(256), 0, stream,
                       w_up, wuT, w_gate, wgT, 8, HID, FFN_);

    // fused: ug GEMM (1280 blocks) + w_down transpose (1024 blocks)
    hipLaunchKernelGGL(fused_ug, dim3(NGEMM + 1024), dim3(256), 0, stream,
                       Xg, wuT, wgT, expert_off, ntile_g, tte, ttm, H1,
                       w_down, wdT);

    hipLaunchKernelGGL(moe_down, dim3(HID / 64, MAXTILE), dim3(256), 0, stream,
                       H1, wdT, expert_off, ntile_g, tte, ttm, tok, wgt, out);
}